// Round 2
// baseline (6368.176 us; speedup 1.0000x reference)
//
#include <hip/hip_runtime.h>

#define NHEAD 8
#define CH    16
#define HC    128   // NHEAD*CH
#define INC   128   // in channels
#define EDIM  8
#define NEG   0.2f

__device__ __forceinline__ float lrelu(float v) { return v > 0.f ? v : NEG * v; }

// ---------------- K1: column sums of edge_attr (for mean) ----------------
__global__ void k_attr_sum(const float* __restrict__ ea, float* __restrict__ attr_sum, int E) {
    __shared__ float s[256];
    int d = threadIdx.x & 7;
    int tot = gridDim.x * blockDim.x;
    int idx = (blockIdx.x * blockDim.x + threadIdx.x) >> 3;
    int stride = tot >> 3;
    float acc = 0.f;
    for (int e = idx; e < E; e += stride) acc += ea[(size_t)e * EDIM + d];
    s[threadIdx.x] = acc;
    __syncthreads();
    for (int off = 128; off >= 8; off >>= 1) {
        if (threadIdx.x < off) s[threadIdx.x] += s[threadIdx.x + off];
        __syncthreads();
    }
    if (threadIdx.x < 8) atomicAdd(&attr_sum[threadIdx.x], s[threadIdx.x]);
}

// ---------------- K2: loop_emb = mean_attr @ W_e ----------------
__global__ void k_loop_emb(const float* __restrict__ attr_sum, const float* __restrict__ We,
                           float* __restrict__ loop_emb, float invE) {
    int j = threadIdx.x;  // 0..127
    float acc = 0.f;
    #pragma unroll
    for (int d = 0; d < EDIM; ++d) acc += attr_sum[d] * invE * We[d * HC + j];
    loop_emb[j] = acc;
}

// ---------------- K3: x_l = x@W_l+b_l ; x_r = x@W_r+b_r ----------------
// thread = (node, tile of 16 output cols), computes both L and R.
__global__ void k_gemm(const float* __restrict__ x,
                       const float* __restrict__ Wl, const float* __restrict__ bl,
                       const float* __restrict__ Wr, const float* __restrict__ br,
                       float* __restrict__ xl, float* __restrict__ xr, int N) {
    int t = blockIdx.x * blockDim.x + threadIdx.x;
    int node = t >> 3;
    if (node >= N) return;
    int tile = (t & 7) * 16;
    float4 accl[4], accr[4];
    #pragma unroll
    for (int q = 0; q < 4; ++q) {
        accl[q] = *(const float4*)(bl + tile + q * 4);
        accr[q] = *(const float4*)(br + tile + q * 4);
    }
    const float* xrow = x + (size_t)node * INC;
    for (int k4 = 0; k4 < INC; k4 += 4) {
        float4 xv = *(const float4*)(xrow + k4);
        float xs[4] = {xv.x, xv.y, xv.z, xv.w};
        #pragma unroll
        for (int kk = 0; kk < 4; ++kk) {
            const float4* wl4 = (const float4*)(Wl + (size_t)(k4 + kk) * HC + tile);
            const float4* wr4 = (const float4*)(Wr + (size_t)(k4 + kk) * HC + tile);
            float xk = xs[kk];
            #pragma unroll
            for (int q = 0; q < 4; ++q) {
                float4 a = wl4[q], b = wr4[q];
                accl[q].x += xk * a.x; accl[q].y += xk * a.y;
                accl[q].z += xk * a.z; accl[q].w += xk * a.w;
                accr[q].x += xk * b.x; accr[q].y += xk * b.y;
                accr[q].z += xk * b.z; accr[q].w += xk * b.w;
            }
        }
    }
    float4* xlo = (float4*)(xl + (size_t)node * HC + tile);
    float4* xro = (float4*)(xr + (size_t)node * HC + tile);
    #pragma unroll
    for (int q = 0; q < 4; ++q) { xlo[q] = accl[q]; xro[q] = accr[q]; }
}

// ---------------- K4: fused edge pass ----------------
// thread = (edge, head). w = exp(logit) (no max-sub needed; logits bounded ~|10|).
// Accumulate segsum[dst][h] += w ; out[dst][h*16+c] += w * x_l[src][h*16+c].
__global__ void k_edge(const int* __restrict__ ei, const float* __restrict__ ea,
                       const float* __restrict__ We, const float* __restrict__ att,
                       const float* __restrict__ xl, const float* __restrict__ xr,
                       const float* __restrict__ loop_emb,
                       float* __restrict__ segsum, float* __restrict__ out,
                       int E, int N) {
    long long t = (long long)blockIdx.x * blockDim.x + threadIdx.x;
    long long ET8 = (long long)(E + N) * NHEAD;
    if (t >= ET8) return;
    int e = (int)(t >> 3);
    int h = (int)(t & 7);
    int src, dst;
    float4 emb[4];
    const float4* We4 = (const float4*)We;
    if (e < E) {
        src = ei[e];
        dst = ei[E + e];
        float4 a0 = *(const float4*)(ea + (size_t)e * EDIM);
        float4 a1 = *(const float4*)(ea + (size_t)e * EDIM + 4);
        float av[8] = {a0.x, a0.y, a0.z, a0.w, a1.x, a1.y, a1.z, a1.w};
        #pragma unroll
        for (int q = 0; q < 4; ++q) emb[q] = make_float4(0.f, 0.f, 0.f, 0.f);
        #pragma unroll
        for (int d = 0; d < EDIM; ++d) {
            float ad = av[d];
            #pragma unroll
            for (int q = 0; q < 4; ++q) {
                float4 w = We4[d * 32 + h * 4 + q];
                emb[q].x += ad * w.x; emb[q].y += ad * w.y;
                emb[q].z += ad * w.z; emb[q].w += ad * w.w;
            }
        }
    } else {
        int n = e - E;
        src = n; dst = n;
        const float4* L4 = (const float4*)loop_emb;
        #pragma unroll
        for (int q = 0; q < 4; ++q) emb[q] = L4[h * 4 + q];
    }
    const float4* xls = (const float4*)(xl + (size_t)src * HC + h * CH);
    const float4* xrd = (const float4*)(xr + (size_t)dst * HC + h * CH);
    const float4* at4 = (const float4*)(att + h * CH);
    float logit = 0.f;
    float xvf[16];
    #pragma unroll
    for (int q = 0; q < 4; ++q) {
        float4 a = xls[q], b = xrd[q], at = at4[q];
        xvf[q * 4 + 0] = a.x; xvf[q * 4 + 1] = a.y;
        xvf[q * 4 + 2] = a.z; xvf[q * 4 + 3] = a.w;
        float m0 = lrelu(a.x + b.x + emb[q].x);
        float m1 = lrelu(a.y + b.y + emb[q].y);
        float m2 = lrelu(a.z + b.z + emb[q].z);
        float m3 = lrelu(a.w + b.w + emb[q].w);
        logit += m0 * at.x + m1 * at.y + m2 * at.z + m3 * at.w;
    }
    float w = __expf(logit);
    atomicAdd(&segsum[(size_t)dst * NHEAD + h], w);
    float* op = out + (size_t)dst * HC + h * CH;
    #pragma unroll
    for (int c = 0; c < CH; ++c) atomicAdd(op + c, w * xvf[c]);
}

// ---------------- K5: normalize + bias ----------------
__global__ void k_final(float* __restrict__ out, const float* __restrict__ segsum,
                        const float* __restrict__ bias, int N) {
    int t = blockIdx.x * blockDim.x + threadIdx.x;
    if (t >= N * HC) return;
    int n = t >> 7;
    int hc = t & 127;
    int h = hc >> 4;
    out[t] = out[t] / (segsum[(size_t)n * NHEAD + h] + 1e-16f) + bias[hc];
}

extern "C" void kernel_launch(void* const* d_in, const int* in_sizes, int n_in,
                              void* d_out, int out_size, void* d_ws, size_t ws_size,
                              hipStream_t stream) {
    int N = in_sizes[0] / INC;
    int E = in_sizes[1] / 2;
    const float* x    = (const float*)d_in[0];
    const int*   ei   = (const int*)d_in[1];   // harness delivers integer inputs as int32
    const float* ea   = (const float*)d_in[2];
    const float* Wl   = (const float*)d_in[3];
    const float* bl   = (const float*)d_in[4];
    const float* Wr   = (const float*)d_in[5];
    const float* br   = (const float*)d_in[6];
    const float* We   = (const float*)d_in[7];
    const float* att  = (const float*)d_in[8];
    const float* bias = (const float*)d_in[9];
    float* out = (float*)d_out;

    float* ws       = (float*)d_ws;
    float* xl       = ws;
    float* xr       = xl + (size_t)N * HC;
    float* segsum   = xr + (size_t)N * HC;
    float* attr_sum = segsum + (size_t)N * NHEAD;
    float* loop_emb = attr_sum + 8;

    // zero accumulators (out is the numerator accumulator; ws is poisoned 0xAA)
    hipMemsetAsync(out, 0, (size_t)N * HC * sizeof(float), stream);
    hipMemsetAsync(segsum, 0, ((size_t)N * NHEAD + 8) * sizeof(float), stream);

    k_attr_sum<<<512, 256, 0, stream>>>(ea, attr_sum, E);
    k_loop_emb<<<1, HC, 0, stream>>>(attr_sum, We, loop_emb, 1.0f / (float)E);

    int gemm_threads = N * 8;
    k_gemm<<<(gemm_threads + 255) / 256, 256, 0, stream>>>(x, Wl, bl, Wr, br, xl, xr, N);

    long long ET8 = (long long)(E + N) * NHEAD;
    int edge_blocks = (int)((ET8 + 255) / 256);
    k_edge<<<edge_blocks, 256, 0, stream>>>(ei, ea, We, att, xl, xr, loop_emb, segsum, out, E, N);

    int fin_threads = N * HC;
    k_final<<<(fin_threads + 255) / 256, 256, 0, stream>>>(out, segsum, bias, N);
}

// Round 3
// 803.705 us; speedup vs baseline: 7.9235x; 7.9235x over previous
//
#include <hip/hip_runtime.h>

#define NHEAD 8
#define CH    16
#define HC    128   // NHEAD*CH
#define INC   128   // in channels
#define EDIM  8
#define NEG   0.2f

__device__ __forceinline__ float lrelu(float v) { return v > 0.f ? v : NEG * v; }

// ---------------- K1: column sums of edge_attr (for mean) ----------------
__global__ void k_attr_sum(const float* __restrict__ ea, float* __restrict__ attr_sum, int E) {
    __shared__ float s[256];
    int d = threadIdx.x & 7;
    int tot = gridDim.x * blockDim.x;
    int idx = (blockIdx.x * blockDim.x + threadIdx.x) >> 3;
    int stride = tot >> 3;
    float acc = 0.f;
    for (int e = idx; e < E; e += stride) acc += ea[(size_t)e * EDIM + d];
    s[threadIdx.x] = acc;
    __syncthreads();
    for (int off = 128; off >= 8; off >>= 1) {
        if (threadIdx.x < off) s[threadIdx.x] += s[threadIdx.x + off];
        __syncthreads();
    }
    if (threadIdx.x < 8) atomicAdd(&attr_sum[threadIdx.x], s[threadIdx.x]);
}

// ---------------- K2: loop_emb = mean_attr @ W_e ----------------
__global__ void k_loop_emb(const float* __restrict__ attr_sum, const float* __restrict__ We,
                           float* __restrict__ loop_emb, float invE) {
    int j = threadIdx.x;  // 0..127
    float acc = 0.f;
    #pragma unroll
    for (int d = 0; d < EDIM; ++d) acc += attr_sum[d] * invE * We[d * HC + j];
    loop_emb[j] = acc;
}

// ---------------- K3: x_l = x@W_l+b_l ; x_r = x@W_r+b_r ----------------
__global__ void k_gemm(const float* __restrict__ x,
                       const float* __restrict__ Wl, const float* __restrict__ bl,
                       const float* __restrict__ Wr, const float* __restrict__ br,
                       float* __restrict__ xl, float* __restrict__ xr, int N) {
    int t = blockIdx.x * blockDim.x + threadIdx.x;
    int node = t >> 3;
    if (node >= N) return;
    int tile = (t & 7) * 16;
    float4 accl[4], accr[4];
    #pragma unroll
    for (int q = 0; q < 4; ++q) {
        accl[q] = *(const float4*)(bl + tile + q * 4);
        accr[q] = *(const float4*)(br + tile + q * 4);
    }
    const float* xrow = x + (size_t)node * INC;
    for (int k4 = 0; k4 < INC; k4 += 4) {
        float4 xv = *(const float4*)(xrow + k4);
        float xs[4] = {xv.x, xv.y, xv.z, xv.w};
        #pragma unroll
        for (int kk = 0; kk < 4; ++kk) {
            const float4* wl4 = (const float4*)(Wl + (size_t)(k4 + kk) * HC + tile);
            const float4* wr4 = (const float4*)(Wr + (size_t)(k4 + kk) * HC + tile);
            float xk = xs[kk];
            #pragma unroll
            for (int q = 0; q < 4; ++q) {
                float4 a = wl4[q], b = wr4[q];
                accl[q].x += xk * a.x; accl[q].y += xk * a.y;
                accl[q].z += xk * a.z; accl[q].w += xk * a.w;
                accr[q].x += xk * b.x; accr[q].y += xk * b.y;
                accr[q].z += xk * b.z; accr[q].w += xk * b.w;
            }
        }
    }
    float4* xlo = (float4*)(xl + (size_t)node * HC + tile);
    float4* xro = (float4*)(xr + (size_t)node * HC + tile);
    #pragma unroll
    for (int q = 0; q < 4; ++q) { xlo[q] = accl[q]; xro[q] = accr[q]; }
}

// ---------------- K4a: histogram of dst ----------------
__global__ void k_hist(const int* __restrict__ ei, int* __restrict__ cnt, int E) {
    int t = blockIdx.x * blockDim.x + threadIdx.x;
    if (t < E) atomicAdd(&cnt[ei[E + t]], 1);
}

// ---------------- K4b: single-block exclusive scan (N=50k) ----------------
__global__ void k_scan(const int* __restrict__ cnt, int* __restrict__ off, int N) {
    __shared__ int s[1024];
    __shared__ int carry_s;
    if (threadIdx.x == 0) carry_s = 0;
    __syncthreads();
    int nchunk = (N + 1023) >> 10;
    for (int c = 0; c < nchunk; ++c) {
        int i = (c << 10) + threadIdx.x;
        int v = (i < N) ? cnt[i] : 0;
        s[threadIdx.x] = v;
        __syncthreads();
        for (int d = 1; d < 1024; d <<= 1) {
            int t = (threadIdx.x >= d) ? s[threadIdx.x - d] : 0;
            __syncthreads();
            s[threadIdx.x] += t;
            __syncthreads();
        }
        int carry = carry_s;
        if (i < N) off[i] = carry + s[threadIdx.x] - v;  // exclusive
        __syncthreads();
        if (threadIdx.x == 1023) carry_s = carry + s[1023];
        __syncthreads();
    }
    if (threadIdx.x == 0) off[N] = carry_s;
}

// ---------------- K4c: scatter edge ids into CSR order ----------------
__global__ void k_scatter(const int* __restrict__ ei, const int* __restrict__ off,
                          int* __restrict__ cur, int* __restrict__ eid, int E) {
    int t = blockIdx.x * blockDim.x + threadIdx.x;
    if (t >= E) return;
    int dst = ei[E + t];
    int pos = off[dst] + atomicAdd(&cur[dst], 1);
    eid[pos] = t;
}

// ---------------- K5: one wave per dst node — register reduction ----------------
// lane l owns channels (2l, 2l+1); head h = l>>3; logit reduced over 8-lane group.
__global__ void k_gather(const int* __restrict__ ei, const float* __restrict__ ea,
                         const float* __restrict__ We, const float* __restrict__ att,
                         const float* __restrict__ xl, const float* __restrict__ xr,
                         const float* __restrict__ loop_emb, const float* __restrict__ bias,
                         const int* __restrict__ off, const int* __restrict__ eid,
                         float* __restrict__ out, int E, int N) {
    int wave = (blockIdx.x * blockDim.x + threadIdx.x) >> 6;
    int lane = threadIdx.x & 63;
    if (wave >= N) return;
    int dst = wave;
    int hc = lane * 2;

    // loop-invariant register hoists
    float we0[EDIM], we1[EDIM];
    #pragma unroll
    for (int d = 0; d < EDIM; ++d) { we0[d] = We[d * HC + hc]; we1[d] = We[d * HC + hc + 1]; }
    float a0 = att[hc], a1 = att[hc + 1];
    float2 xrv = *(const float2*)(xr + (size_t)dst * HC + hc);

    float acc0 = 0.f, acc1 = 0.f, segw = 0.f;

    // self-loop (src = dst, emb = loop_emb)
    {
        float2 xlv = *(const float2*)(xl + (size_t)dst * HC + hc);
        float m0 = lrelu(xlv.x + xrv.x + loop_emb[hc]);
        float m1 = lrelu(xlv.y + xrv.y + loop_emb[hc + 1]);
        float p = m0 * a0 + m1 * a1;
        p += __shfl_xor(p, 1); p += __shfl_xor(p, 2); p += __shfl_xor(p, 4);
        float w = __expf(p);
        segw += w; acc0 += w * xlv.x; acc1 += w * xlv.y;
    }

    int beg = off[dst], end = off[dst + 1];
    for (int i = beg; i < end; ++i) {
        int e = eid[i];            // wave-uniform -> scalar loads
        int src = ei[e];
        float emb0 = 0.f, emb1 = 0.f;
        #pragma unroll
        for (int d = 0; d < EDIM; ++d) {
            float ad = ea[(size_t)e * EDIM + d];
            emb0 += ad * we0[d]; emb1 += ad * we1[d];
        }
        float2 xlv = *(const float2*)(xl + (size_t)src * HC + hc);
        float m0 = lrelu(xlv.x + xrv.x + emb0);
        float m1 = lrelu(xlv.y + xrv.y + emb1);
        float p = m0 * a0 + m1 * a1;
        p += __shfl_xor(p, 1); p += __shfl_xor(p, 2); p += __shfl_xor(p, 4);
        float w = __expf(p);
        segw += w; acc0 += w * xlv.x; acc1 += w * xlv.y;
    }

    float inv = 1.f / (segw + 1e-16f);
    float2 o = make_float2(acc0 * inv + bias[hc], acc1 * inv + bias[hc + 1]);
    *(float2*)(out + (size_t)dst * HC + hc) = o;
}

extern "C" void kernel_launch(void* const* d_in, const int* in_sizes, int n_in,
                              void* d_out, int out_size, void* d_ws, size_t ws_size,
                              hipStream_t stream) {
    int N = in_sizes[0] / INC;
    int E = in_sizes[1] / 2;
    const float* x    = (const float*)d_in[0];
    const int*   ei   = (const int*)d_in[1];   // int32 from harness
    const float* ea   = (const float*)d_in[2];
    const float* Wl   = (const float*)d_in[3];
    const float* bl   = (const float*)d_in[4];
    const float* Wr   = (const float*)d_in[5];
    const float* br   = (const float*)d_in[6];
    const float* We   = (const float*)d_in[7];
    const float* att  = (const float*)d_in[8];
    const float* bias = (const float*)d_in[9];
    float* out = (float*)d_out;

    // workspace layout
    float* ws       = (float*)d_ws;
    float* xl       = ws;                                  // N*HC
    float* xr       = xl + (size_t)N * HC;                 // N*HC
    float* attr_sum = xr + (size_t)N * HC;                 // 8
    float* loop_emb = attr_sum + 8;                        // 128
    int*   off      = (int*)(loop_emb + HC);               // N+1
    int*   cnt      = off + (N + 1);                       // N (also reused as cursor)
    int*   eid      = cnt + N;                             // E

    hipMemsetAsync(attr_sum, 0, 8 * sizeof(float), stream);
    hipMemsetAsync(cnt, 0, (size_t)N * sizeof(int), stream);

    k_attr_sum<<<512, 256, 0, stream>>>(ea, attr_sum, E);
    k_loop_emb<<<1, HC, 0, stream>>>(attr_sum, We, loop_emb, 1.0f / (float)E);

    k_gemm<<<(N * 8 + 255) / 256, 256, 0, stream>>>(x, Wl, bl, Wr, br, xl, xr, N);

    k_hist<<<(E + 255) / 256, 256, 0, stream>>>(ei, cnt, E);
    k_scan<<<1, 1024, 0, stream>>>(cnt, off, N);
    hipMemsetAsync(cnt, 0, (size_t)N * sizeof(int), stream);  // cursor
    k_scatter<<<(E + 255) / 256, 256, 0, stream>>>(ei, off, cnt, eid, E);

    k_gather<<<(N * 64 + 255) / 256, 256, 0, stream>>>(ei, ea, We, att, xl, xr,
                                                       loop_emb, bias, off, eid, out, E, N);
}

// Round 4
// 408.098 us; speedup vs baseline: 15.6045x; 1.9694x over previous
//
#include <hip/hip_runtime.h>

#define NHEAD 8
#define CH    16
#define HC    128   // NHEAD*CH
#define INC   128   // in channels
#define EDIM  8
#define NEG   0.2f

#define MB    64    // nodes per gemm block
#define KS    32    // gemm K-step

__device__ __forceinline__ float lrelu(float v) { return v > 0.f ? v : NEG * v; }

// ---------------- K1: column sums of edge_attr (for mean) ----------------
__global__ void k_attr_sum(const float* __restrict__ ea, float* __restrict__ attr_sum, int E) {
    __shared__ float s[256];
    int d = threadIdx.x & 7;
    int tot = gridDim.x * blockDim.x;
    int idx = (blockIdx.x * blockDim.x + threadIdx.x) >> 3;
    int stride = tot >> 3;
    float acc = 0.f;
    for (int e = idx; e < E; e += stride) acc += ea[(size_t)e * EDIM + d];
    s[threadIdx.x] = acc;
    __syncthreads();
    for (int off = 128; off >= 8; off >>= 1) {
        if (threadIdx.x < off) s[threadIdx.x] += s[threadIdx.x + off];
        __syncthreads();
    }
    if (threadIdx.x < 8) atomicAdd(&attr_sum[threadIdx.x], s[threadIdx.x]);
}

// ---------------- K2: loop_emb = mean_attr @ W_e ----------------
__global__ void k_loop_emb(const float* __restrict__ attr_sum, const float* __restrict__ We,
                           float* __restrict__ loop_emb, float invE) {
    int j = threadIdx.x;  // 0..127
    float acc = 0.f;
    #pragma unroll
    for (int d = 0; d < EDIM; ++d) acc += attr_sum[d] * invE * We[d * HC + j];
    loop_emb[j] = acc;
}

// ---------------- K3 v2: LDS-tiled, register-blocked dual GEMM ----------------
// block = 64 nodes x 256 cols (both L and R). 256 threads: col-thread c = t&31
// owns 4 cols of L and 4 of R; node subgroup ng = t>>5 owns 8 nodes.
__global__ __launch_bounds__(256) void k_gemm(
        const float* __restrict__ x,
        const float* __restrict__ Wl, const float* __restrict__ bl,
        const float* __restrict__ Wr, const float* __restrict__ br,
        float* __restrict__ xl, float* __restrict__ xr, int N) {
    __shared__ float xs[MB][KS];    // 8 KB
    __shared__ float wls[KS][HC];   // 16 KB
    __shared__ float wrs[KS][HC];   // 16 KB

    int n0 = blockIdx.x * MB;
    int c  = threadIdx.x & 31;
    int ng = threadIdx.x >> 5;

    float4 al[8], ar[8];
    float4 blv = *(const float4*)(bl + c * 4);
    float4 brv = *(const float4*)(br + c * 4);
    #pragma unroll
    for (int n = 0; n < 8; ++n) { al[n] = blv; ar[n] = brv; }

    for (int k0 = 0; k0 < INC; k0 += KS) {
        // stage W tiles: 1024 float4 each
        #pragma unroll
        for (int q = 0; q < 4; ++q) {
            int f = threadIdx.x + 256 * q;
            int r = f >> 5, c4 = f & 31;
            ((float4*)wls)[f] = *(const float4*)(Wl + (size_t)(k0 + r) * HC + c4 * 4);
            ((float4*)wrs)[f] = *(const float4*)(Wr + (size_t)(k0 + r) * HC + c4 * 4);
        }
        // stage x tile: 512 float4
        #pragma unroll
        for (int q = 0; q < 2; ++q) {
            int f = threadIdx.x + 256 * q;
            int n = f >> 3, c4 = f & 7;
            int node = n0 + n; if (node >= N) node = N - 1;
            ((float4*)xs)[f] = *(const float4*)(x + (size_t)node * INC + k0 + c4 * 4);
        }
        __syncthreads();
        #pragma unroll
        for (int k = 0; k < KS; ++k) {
            float4 wl = *(const float4*)&wls[k][c * 4];
            float4 wr = *(const float4*)&wrs[k][c * 4];
            #pragma unroll
            for (int n = 0; n < 8; ++n) {
                float xv = xs[ng * 8 + n][k];
                al[n].x += xv * wl.x; al[n].y += xv * wl.y;
                al[n].z += xv * wl.z; al[n].w += xv * wl.w;
                ar[n].x += xv * wr.x; ar[n].y += xv * wr.y;
                ar[n].z += xv * wr.z; ar[n].w += xv * wr.w;
            }
        }
        __syncthreads();
    }
    #pragma unroll
    for (int n = 0; n < 8; ++n) {
        int node = n0 + ng * 8 + n;
        if (node < N) {
            *(float4*)(xl + (size_t)node * HC + c * 4) = al[n];
            *(float4*)(xr + (size_t)node * HC + c * 4) = ar[n];
        }
    }
}

// ---------------- K4a: histogram of dst ----------------
__global__ void k_hist(const int* __restrict__ ei, int* __restrict__ cnt, int E) {
    int t = blockIdx.x * blockDim.x + threadIdx.x;
    if (t < E) atomicAdd(&cnt[ei[E + t]], 1);
}

// ---------------- K4b: single-block exclusive scan (N=50k) ----------------
__global__ void k_scan(const int* __restrict__ cnt, int* __restrict__ off, int N) {
    __shared__ int s[1024];
    __shared__ int carry_s;
    if (threadIdx.x == 0) carry_s = 0;
    __syncthreads();
    int nchunk = (N + 1023) >> 10;
    for (int c = 0; c < nchunk; ++c) {
        int i = (c << 10) + threadIdx.x;
        int v = (i < N) ? cnt[i] : 0;
        s[threadIdx.x] = v;
        __syncthreads();
        for (int d = 1; d < 1024; d <<= 1) {
            int t = (threadIdx.x >= d) ? s[threadIdx.x - d] : 0;
            __syncthreads();
            s[threadIdx.x] += t;
            __syncthreads();
        }
        int carry = carry_s;
        if (i < N) off[i] = carry + s[threadIdx.x] - v;  // exclusive
        __syncthreads();
        if (threadIdx.x == 1023) carry_s = carry + s[1023];
        __syncthreads();
    }
    if (threadIdx.x == 0) off[N] = carry_s;
}

// ---------------- K4c: scatter edge ids into CSR order ----------------
__global__ void k_scatter(const int* __restrict__ ei, const int* __restrict__ off,
                          int* __restrict__ cur, int* __restrict__ eid, int E) {
    int t = blockIdx.x * blockDim.x + threadIdx.x;
    if (t >= E) return;
    int dst = ei[E + t];
    int pos = off[dst] + atomicAdd(&cur[dst], 1);
    eid[pos] = t;
}

// ---------------- K5 v2: one wave per dst node, pipelined gather ----------------
__global__ void k_gather(const int* __restrict__ ei, const float* __restrict__ ea,
                         const float* __restrict__ We, const float* __restrict__ att,
                         const float* __restrict__ xl, const float* __restrict__ xr,
                         const float* __restrict__ loop_emb, const float* __restrict__ bias,
                         const int* __restrict__ off, const int* __restrict__ eid,
                         float* __restrict__ out, int E, int N) {
    int wave = (blockIdx.x * blockDim.x + threadIdx.x) >> 6;
    int lane = threadIdx.x & 63;
    if (wave >= N) return;
    int dst = wave;
    int hc = lane * 2;

    float we0[EDIM], we1[EDIM];
    #pragma unroll
    for (int d = 0; d < EDIM; ++d) { we0[d] = We[d * HC + hc]; we1[d] = We[d * HC + hc + 1]; }
    float a0 = att[hc], a1 = att[hc + 1];
    float2 xrv = *(const float2*)(xr + (size_t)dst * HC + hc);

    float acc0 = 0.f, acc1 = 0.f, segw = 0.f;

    // self-loop (src = dst, emb = loop_emb)
    {
        float2 xlv = *(const float2*)(xl + (size_t)dst * HC + hc);
        float m0 = lrelu(xlv.x + xrv.x + loop_emb[hc]);
        float m1 = lrelu(xlv.y + xrv.y + loop_emb[hc + 1]);
        float p = m0 * a0 + m1 * a1;
        p += __shfl_xor(p, 1); p += __shfl_xor(p, 2); p += __shfl_xor(p, 4);
        float w = __expf(p);
        segw += w; acc0 += w * xlv.x; acc1 += w * xlv.y;
    }

    int beg = off[dst], end = off[dst + 1];
    for (int i0 = beg; i0 < end; i0 += 64) {
        int cnt = end - i0; if (cnt > 64) cnt = 64;
        int e = 0, src = 0;
        if (lane < cnt) { e = eid[i0 + lane]; src = ei[e]; }
        // prefetch edge 0
        int sj = __shfl(src, 0), ej = __shfl(e, 0);
        float2 xp  = *(const float2*)(xl + (size_t)sj * HC + hc);
        float4 ap0 = *(const float4*)(ea + (size_t)ej * EDIM);
        float4 ap1 = *(const float4*)(ea + (size_t)ej * EDIM + 4);
        for (int j = 0; j < cnt; ++j) {
            float2 xv = xp;
            float4 e0 = ap0, e1 = ap1;
            if (j + 1 < cnt) {
                int sn = __shfl(src, j + 1), en = __shfl(e, j + 1);
                xp  = *(const float2*)(xl + (size_t)sn * HC + hc);
                ap0 = *(const float4*)(ea + (size_t)en * EDIM);
                ap1 = *(const float4*)(ea + (size_t)en * EDIM + 4);
            }
            float av[8] = {e0.x, e0.y, e0.z, e0.w, e1.x, e1.y, e1.z, e1.w};
            float emb0 = 0.f, emb1 = 0.f;
            #pragma unroll
            for (int d = 0; d < EDIM; ++d) { emb0 += av[d] * we0[d]; emb1 += av[d] * we1[d]; }
            float m0 = lrelu(xv.x + xrv.x + emb0);
            float m1 = lrelu(xv.y + xrv.y + emb1);
            float p = m0 * a0 + m1 * a1;
            p += __shfl_xor(p, 1); p += __shfl_xor(p, 2); p += __shfl_xor(p, 4);
            float w = __expf(p);
            segw += w; acc0 += w * xv.x; acc1 += w * xv.y;
        }
    }

    float inv = 1.f / (segw + 1e-16f);
    float2 o = make_float2(acc0 * inv + bias[hc], acc1 * inv + bias[hc + 1]);
    *(float2*)(out + (size_t)dst * HC + hc) = o;
}

extern "C" void kernel_launch(void* const* d_in, const int* in_sizes, int n_in,
                              void* d_out, int out_size, void* d_ws, size_t ws_size,
                              hipStream_t stream) {
    int N = in_sizes[0] / INC;
    int E = in_sizes[1] / 2;
    const float* x    = (const float*)d_in[0];
    const int*   ei   = (const int*)d_in[1];   // int32 from harness
    const float* ea   = (const float*)d_in[2];
    const float* Wl   = (const float*)d_in[3];
    const float* bl   = (const float*)d_in[4];
    const float* Wr   = (const float*)d_in[5];
    const float* br   = (const float*)d_in[6];
    const float* We   = (const float*)d_in[7];
    const float* att  = (const float*)d_in[8];
    const float* bias = (const float*)d_in[9];
    float* out = (float*)d_out;

    // workspace layout
    float* ws       = (float*)d_ws;
    float* xl       = ws;                                  // N*HC
    float* xr       = xl + (size_t)N * HC;                 // N*HC
    float* attr_sum = xr + (size_t)N * HC;                 // 8
    float* loop_emb = attr_sum + 8;                        // 128
    int*   off      = (int*)(loop_emb + HC);               // N+1
    int*   cnt      = off + (N + 1);                       // N (also reused as cursor)
    int*   eid      = cnt + N;                             // E

    hipMemsetAsync(attr_sum, 0, 8 * sizeof(float), stream);
    hipMemsetAsync(cnt, 0, (size_t)N * sizeof(int), stream);

    k_attr_sum<<<512, 256, 0, stream>>>(ea, attr_sum, E);
    k_loop_emb<<<1, HC, 0, stream>>>(attr_sum, We, loop_emb, 1.0f / (float)E);

    k_gemm<<<(N + MB - 1) / MB, 256, 0, stream>>>(x, Wl, bl, Wr, br, xl, xr, N);

    k_hist<<<(E + 255) / 256, 256, 0, stream>>>(ei, cnt, E);
    k_scan<<<1, 1024, 0, stream>>>(cnt, off, N);
    hipMemsetAsync(cnt, 0, (size_t)N * sizeof(int), stream);  // cursor
    k_scatter<<<(E + 255) / 256, 256, 0, stream>>>(ei, off, cnt, eid, E);

    k_gather<<<(N * 64 + 255) / 256, 256, 0, stream>>>(ei, ea, We, att, xl, xr,
                                                       loop_emb, bias, off, eid, out, E, N);
}

// Round 5
// 288.602 us; speedup vs baseline: 22.0656x; 1.4140x over previous
//
#include <hip/hip_runtime.h>

#define NHEAD 8
#define CH    16
#define HC    128   // NHEAD*CH
#define INC   128   // in channels
#define EDIM  8
#define NEG   0.2f

typedef _Float16 h8 __attribute__((ext_vector_type(8)));
typedef _Float16 h2 __attribute__((ext_vector_type(2)));
typedef float    f4 __attribute__((ext_vector_type(4)));

__device__ __forceinline__ float lrelu(float v) { return v > 0.f ? v : NEG * v; }

// ---------------- K1: column sums of edge_attr (for mean) ----------------
__global__ void k_attr_sum(const float* __restrict__ ea, float* __restrict__ attr_sum, int E) {
    __shared__ float s[256];
    int d = threadIdx.x & 7;
    int tot = gridDim.x * blockDim.x;
    int idx = (blockIdx.x * blockDim.x + threadIdx.x) >> 3;
    int stride = tot >> 3;
    float acc = 0.f;
    for (int e = idx; e < E; e += stride) acc += ea[(size_t)e * EDIM + d];
    s[threadIdx.x] = acc;
    __syncthreads();
    for (int off = 128; off >= 8; off >>= 1) {
        if (threadIdx.x < off) s[threadIdx.x] += s[threadIdx.x + off];
        __syncthreads();
    }
    if (threadIdx.x < 8) atomicAdd(&attr_sum[threadIdx.x], s[threadIdx.x]);
}

// ---------------- K2: loop_emb = mean_attr @ W_e ----------------
__global__ void k_loop_emb(const float* __restrict__ attr_sum, const float* __restrict__ We,
                           float* __restrict__ loop_emb, float invE) {
    int j = threadIdx.x;  // 0..127
    float acc = 0.f;
    #pragma unroll
    for (int d = 0; d < EDIM; ++d) acc += attr_sum[d] * invE * We[d * HC + j];
    loop_emb[j] = acc;
}

// ---------------- K3a: pack W = [Wl|Wr] into B-fragment order, fp16 ----------------
// packed[((t*4 + kb)*64 + l)*8 + j] = W[kb*32 + (l>>4)*8 + j][t*16 + (l&15)]
__global__ void k_packW(const float* __restrict__ Wl, const float* __restrict__ Wr,
                        _Float16* __restrict__ packed) {
    int id = blockIdx.x * blockDim.x + threadIdx.x;  // 0..4095
    int l  = id & 63;
    int kb = (id >> 6) & 3;
    int t  = id >> 8;           // 0..15
    int col = t * 16 + (l & 15);
    const float* W = (col < HC) ? Wl : Wr;
    int c = col & 127;
    int kbase = kb * 32 + (l >> 4) * 8;
    _Float16* dst = packed + (size_t)id * 8;
    #pragma unroll
    for (int j = 0; j < 8; ++j) dst[j] = (_Float16)W[(size_t)(kbase + j) * HC + c];
}

// ---------------- K3b: MFMA fp16 dual GEMM -> xh[N][256] (xl | xr) ----------------
// block = 1 M-tile (16 nodes) x 256 cols; wave w owns cols [64w, 64w+64).
__global__ __launch_bounds__(256) void k_gemm_mfma(
        const float* __restrict__ x, const _Float16* __restrict__ packed,
        const float* __restrict__ bl, const float* __restrict__ br,
        _Float16* __restrict__ xh, int N) {
    int m0 = blockIdx.x * 16;
    int w  = threadIdx.x >> 6;
    int l  = threadIdx.x & 63;

    const h8* pk = (const h8*)packed;
    h8 bfrag[4][4];  // [ntile][kb]
    #pragma unroll
    for (int t4 = 0; t4 < 4; ++t4)
        #pragma unroll
        for (int kb = 0; kb < 4; ++kb)
            bfrag[t4][kb] = pk[(size_t)(((w * 4 + t4) * 4 + kb) * 64 + l)];

    int row = m0 + (l & 15);
    if (row >= N) row = N - 1;
    int g = l >> 4;
    const float* xp = x + (size_t)row * INC + g * 8;
    h8 afrag[4];
    #pragma unroll
    for (int kb = 0; kb < 4; ++kb) {
        float4 u = *(const float4*)(xp + kb * 32);
        float4 v = *(const float4*)(xp + kb * 32 + 4);
        h8 a;
        a[0] = (_Float16)u.x; a[1] = (_Float16)u.y; a[2] = (_Float16)u.z; a[3] = (_Float16)u.w;
        a[4] = (_Float16)v.x; a[5] = (_Float16)v.y; a[6] = (_Float16)v.z; a[7] = (_Float16)v.w;
        afrag[kb] = a;
    }

    f4 acc[4];
    #pragma unroll
    for (int t4 = 0; t4 < 4; ++t4) { f4 z = {0.f, 0.f, 0.f, 0.f}; acc[t4] = z; }
    #pragma unroll
    for (int kb = 0; kb < 4; ++kb)
        #pragma unroll
        for (int t4 = 0; t4 < 4; ++t4)
            acc[t4] = __builtin_amdgcn_mfma_f32_16x16x32_f16(afrag[kb], bfrag[t4][kb], acc[t4], 0, 0, 0);

    int r0 = (l >> 4) * 4;
    #pragma unroll
    for (int t4 = 0; t4 < 4; ++t4) {
        int col = w * 64 + t4 * 16 + (l & 15);
        float bv = (col < HC) ? bl[col] : br[col - HC];
        #pragma unroll
        for (int j = 0; j < 4; ++j) {
            int node = m0 + r0 + j;
            if (node < N) xh[(size_t)node * 256 + col] = (_Float16)(acc[t4][j] + bv);
        }
    }
}

// ---------------- K4a: histogram of dst ----------------
__global__ void k_hist(const int* __restrict__ ei, int* __restrict__ cnt, int E) {
    int t = blockIdx.x * blockDim.x + threadIdx.x;
    if (t < E) atomicAdd(&cnt[ei[E + t]], 1);
}

// ---------------- K4b: single-block scan, wave-shuffle version ----------------
__global__ void k_scan(const int* __restrict__ cnt, int* __restrict__ off, int N) {
    __shared__ int wpre[16];
    __shared__ int carry_s;
    int lane = threadIdx.x & 63, wid = threadIdx.x >> 6;
    if (threadIdx.x == 0) carry_s = 0;
    __syncthreads();
    for (int base = 0; base < N; base += 1024) {
        int i = base + threadIdx.x;
        int v = (i < N) ? cnt[i] : 0;
        int s = v;
        #pragma unroll
        for (int d = 1; d < 64; d <<= 1) {
            int t = __shfl_up(s, d);
            if (lane >= d) s += t;
        }
        if (lane == 63) wpre[wid] = s;
        __syncthreads();
        if (threadIdx.x == 0) {
            int run = carry_s;
            #pragma unroll
            for (int q = 0; q < 16; ++q) { int t = wpre[q]; wpre[q] = run; run += t; }
            carry_s = run;
        }
        __syncthreads();
        if (i < N) off[i] = wpre[wid] + s - v;  // exclusive
        __syncthreads();
    }
    if (threadIdx.x == 0) off[N] = carry_s;
}

// ---------------- K4c: scatter edge ids into CSR order ----------------
__global__ void k_scatter(const int* __restrict__ ei, const int* __restrict__ off,
                          int* __restrict__ cur, int* __restrict__ eid, int E) {
    int t = blockIdx.x * blockDim.x + threadIdx.x;
    if (t >= E) return;
    int dst = ei[E + t];
    int pos = off[dst] + atomicAdd(&cur[dst], 1);
    eid[pos] = t;
}

// ---------------- K5: one wave per dst node, pipelined gather (fp16 xh) ----------------
__global__ void k_gather(const int* __restrict__ ei, const float* __restrict__ ea,
                         const float* __restrict__ We, const float* __restrict__ att,
                         const _Float16* __restrict__ xh,
                         const float* __restrict__ loop_emb, const float* __restrict__ bias,
                         const int* __restrict__ off, const int* __restrict__ eid,
                         float* __restrict__ out, int E, int N) {
    int wave = (blockIdx.x * blockDim.x + threadIdx.x) >> 6;
    int lane = threadIdx.x & 63;
    if (wave >= N) return;
    int dst = wave;
    int hc = lane * 2;

    float we0[EDIM], we1[EDIM];
    #pragma unroll
    for (int d = 0; d < EDIM; ++d) { we0[d] = We[d * HC + hc]; we1[d] = We[d * HC + hc + 1]; }
    float a0 = att[hc], a1 = att[hc + 1];
    h2 xr2 = *(const h2*)(xh + dst * 256 + HC + hc);
    float xr0 = (float)xr2[0], xr1 = (float)xr2[1];

    float acc0 = 0.f, acc1 = 0.f, segw = 0.f;

    // self-loop (src = dst, emb = loop_emb)
    {
        h2 xl2 = *(const h2*)(xh + dst * 256 + hc);
        float x0 = (float)xl2[0], x1 = (float)xl2[1];
        float m0 = lrelu(x0 + xr0 + loop_emb[hc]);
        float m1 = lrelu(x1 + xr1 + loop_emb[hc + 1]);
        float p = m0 * a0 + m1 * a1;
        p += __shfl_xor(p, 1); p += __shfl_xor(p, 2); p += __shfl_xor(p, 4);
        float w = __expf(p);
        segw += w; acc0 += w * x0; acc1 += w * x1;
    }

    int beg = off[dst], end = off[dst + 1];
    for (int i0 = beg; i0 < end; i0 += 64) {
        int cnt = end - i0; if (cnt > 64) cnt = 64;
        int e = 0, src = 0;
        if (lane < cnt) { e = eid[i0 + lane]; src = ei[e]; }
        int sj = __shfl(src, 0), ej = __shfl(e, 0);
        h2     xp  = *(const h2*)(xh + sj * 256 + hc);
        float4 ap0 = *(const float4*)(ea + ej * EDIM);
        float4 ap1 = *(const float4*)(ea + ej * EDIM + 4);
        for (int j = 0; j < cnt; ++j) {
            h2 xv2 = xp;
            float4 e0 = ap0, e1 = ap1;
            if (j + 1 < cnt) {
                int sn = __shfl(src, j + 1), en = __shfl(e, j + 1);
                xp  = *(const h2*)(xh + sn * 256 + hc);
                ap0 = *(const float4*)(ea + en * EDIM);
                ap1 = *(const float4*)(ea + en * EDIM + 4);
            }
            float x0 = (float)xv2[0], x1 = (float)xv2[1];
            float av[8] = {e0.x, e0.y, e0.z, e0.w, e1.x, e1.y, e1.z, e1.w};
            float emb0 = 0.f, emb1 = 0.f;
            #pragma unroll
            for (int d = 0; d < EDIM; ++d) { emb0 += av[d] * we0[d]; emb1 += av[d] * we1[d]; }
            float m0 = lrelu(x0 + xr0 + emb0);
            float m1 = lrelu(x1 + xr1 + emb1);
            float p = m0 * a0 + m1 * a1;
            p += __shfl_xor(p, 1); p += __shfl_xor(p, 2); p += __shfl_xor(p, 4);
            float w = __expf(p);
            segw += w; acc0 += w * x0; acc1 += w * x1;
        }
    }

    float inv = 1.f / (segw + 1e-16f);
    float2 o = make_float2(acc0 * inv + bias[hc], acc1 * inv + bias[hc + 1]);
    *(float2*)(out + (size_t)dst * HC + hc) = o;
}

extern "C" void kernel_launch(void* const* d_in, const int* in_sizes, int n_in,
                              void* d_out, int out_size, void* d_ws, size_t ws_size,
                              hipStream_t stream) {
    int N = in_sizes[0] / INC;
    int E = in_sizes[1] / 2;
    const float* x    = (const float*)d_in[0];
    const int*   ei   = (const int*)d_in[1];   // int32 from harness
    const float* ea   = (const float*)d_in[2];
    const float* Wl   = (const float*)d_in[3];
    const float* bl   = (const float*)d_in[4];
    const float* Wr   = (const float*)d_in[5];
    const float* br   = (const float*)d_in[6];
    const float* We   = (const float*)d_in[7];
    const float* att  = (const float*)d_in[8];
    const float* bias = (const float*)d_in[9];
    float* out = (float*)d_out;

    // workspace layout
    _Float16* xh      = (_Float16*)d_ws;                   // N*256 halfs (xl | xr)
    float* attr_sum   = (float*)(xh + (size_t)N * 256);    // 8
    float* loop_emb   = attr_sum + 8;                      // 128
    _Float16* packed  = (_Float16*)(loop_emb + HC);        // 32768 halfs
    int*   off        = (int*)(packed + 32768);            // N+1
    int*   cnt        = off + (N + 1);                     // N (reused as cursor)
    int*   eid        = cnt + N;                           // E

    hipMemsetAsync(attr_sum, 0, 8 * sizeof(float), stream);
    hipMemsetAsync(cnt, 0, (size_t)N * sizeof(int), stream);

    k_attr_sum<<<512, 256, 0, stream>>>(ea, attr_sum, E);
    k_loop_emb<<<1, HC, 0, stream>>>(attr_sum, We, loop_emb, 1.0f / (float)E);

    k_packW<<<16, 256, 0, stream>>>(Wl, Wr, packed);
    k_gemm_mfma<<<(N + 15) / 16, 256, 0, stream>>>(x, packed, bl, br, xh, N);

    k_hist<<<(E + 255) / 256, 256, 0, stream>>>(ei, cnt, E);
    k_scan<<<1, 1024, 0, stream>>>(cnt, off, N);
    hipMemsetAsync(cnt, 0, (size_t)N * sizeof(int), stream);  // cursor
    k_scatter<<<(E + 255) / 256, 256, 0, stream>>>(ei, off, cnt, eid, E);

    k_gather<<<(N * 64 + 255) / 256, 256, 0, stream>>>(ei, ea, We, att, xh,
                                                       loop_emb, bias, off, eid, out, E, N);
}

// Round 6
// 224.371 us; speedup vs baseline: 28.3824x; 1.2863x over previous
//
#include <hip/hip_runtime.h>

#define NHEAD 8
#define CH    16
#define HC    128   // NHEAD*CH
#define INC   128   // in channels
#define EDIM  8
#define NEG   0.2f

typedef _Float16 h8 __attribute__((ext_vector_type(8)));
typedef _Float16 h2 __attribute__((ext_vector_type(2)));
typedef float    f4 __attribute__((ext_vector_type(4)));

__device__ __forceinline__ float lrelu(float v) { return v > 0.f ? v : NEG * v; }

// ---------------- K1: column sums of edge_attr (for mean) ----------------
__global__ void k_attr_sum(const float* __restrict__ ea, float* __restrict__ attr_sum, int E) {
    __shared__ float s[256];
    int d = threadIdx.x & 7;
    int tot = gridDim.x * blockDim.x;
    int idx = (blockIdx.x * blockDim.x + threadIdx.x) >> 3;
    int stride = tot >> 3;
    float acc = 0.f;
    for (int e = idx; e < E; e += stride) acc += ea[(size_t)e * EDIM + d];
    s[threadIdx.x] = acc;
    __syncthreads();
    for (int off = 128; off >= 8; off >>= 1) {
        if (threadIdx.x < off) s[threadIdx.x] += s[threadIdx.x + off];
        __syncthreads();
    }
    if (threadIdx.x < 8) atomicAdd(&attr_sum[threadIdx.x], s[threadIdx.x]);
}

// ---------------- K2: loop_emb = mean_attr @ W_e ----------------
__global__ void k_loop_emb(const float* __restrict__ attr_sum, const float* __restrict__ We,
                           float* __restrict__ loop_emb, float invE) {
    int j = threadIdx.x;  // 0..127
    float acc = 0.f;
    #pragma unroll
    for (int d = 0; d < EDIM; ++d) acc += attr_sum[d] * invE * We[d * HC + j];
    loop_emb[j] = acc;
}

// ---------------- K3a: pack W = [Wl|Wr] into B-fragment order, fp16 ----------------
__global__ void k_packW(const float* __restrict__ Wl, const float* __restrict__ Wr,
                        _Float16* __restrict__ packed) {
    int id = blockIdx.x * blockDim.x + threadIdx.x;  // 0..4095
    int l  = id & 63;
    int kb = (id >> 6) & 3;
    int t  = id >> 8;           // 0..15
    int col = t * 16 + (l & 15);
    const float* W = (col < HC) ? Wl : Wr;
    int c = col & 127;
    int kbase = kb * 32 + (l >> 4) * 8;
    _Float16* dst = packed + (size_t)id * 8;
    #pragma unroll
    for (int j = 0; j < 8; ++j) dst[j] = (_Float16)W[(size_t)(kbase + j) * HC + c];
}

// ---------------- K3b: MFMA fp16 dual GEMM, 64 nodes/block ----------------
__global__ __launch_bounds__(256) void k_gemm_mfma(
        const float* __restrict__ x, const _Float16* __restrict__ packed,
        const float* __restrict__ bl, const float* __restrict__ br,
        _Float16* __restrict__ xh, int N) {
    int nb0 = blockIdx.x * 64;
    int w  = threadIdx.x >> 6;
    int l  = threadIdx.x & 63;

    const h8* pk = (const h8*)packed;
    h8 bfrag[4][4];  // [ntile][kb]
    #pragma unroll
    for (int t4 = 0; t4 < 4; ++t4)
        #pragma unroll
        for (int kb = 0; kb < 4; ++kb)
            bfrag[t4][kb] = pk[(size_t)(((w * 4 + t4) * 4 + kb) * 64 + l)];

    float bv[4];
    int cl = l & 15;
    #pragma unroll
    for (int t4 = 0; t4 < 4; ++t4) {
        int col = w * 64 + t4 * 16 + cl;
        bv[t4] = (col < HC) ? bl[col] : br[col - HC];
    }

    int g = l >> 4;
    int r0 = g * 4;
    for (int mt = 0; mt < 4; ++mt) {
        int m0 = nb0 + mt * 16;
        if (m0 >= N) break;
        int row = m0 + cl; if (row >= N) row = N - 1;
        const float* xp = x + (size_t)row * INC + g * 8;
        h8 afrag[4];
        #pragma unroll
        for (int kb = 0; kb < 4; ++kb) {
            float4 u = *(const float4*)(xp + kb * 32);
            float4 v = *(const float4*)(xp + kb * 32 + 4);
            h8 a;
            a[0] = (_Float16)u.x; a[1] = (_Float16)u.y; a[2] = (_Float16)u.z; a[3] = (_Float16)u.w;
            a[4] = (_Float16)v.x; a[5] = (_Float16)v.y; a[6] = (_Float16)v.z; a[7] = (_Float16)v.w;
            afrag[kb] = a;
        }
        f4 acc[4];
        #pragma unroll
        for (int t4 = 0; t4 < 4; ++t4) { f4 z = {0.f, 0.f, 0.f, 0.f}; acc[t4] = z; }
        #pragma unroll
        for (int kb = 0; kb < 4; ++kb)
            #pragma unroll
            for (int t4 = 0; t4 < 4; ++t4)
                acc[t4] = __builtin_amdgcn_mfma_f32_16x16x32_f16(afrag[kb], bfrag[t4][kb], acc[t4], 0, 0, 0);
        #pragma unroll
        for (int t4 = 0; t4 < 4; ++t4) {
            int col = w * 64 + t4 * 16 + cl;
            #pragma unroll
            for (int j = 0; j < 4; ++j) {
                int node = m0 + r0 + j;
                if (node < N) xh[(size_t)node * 256 + col] = (_Float16)(acc[t4][j] + bv[t4]);
            }
        }
    }
}

// ---------------- K4a: histogram of dst ----------------
__global__ void k_hist(const int* __restrict__ ei, int* __restrict__ cnt, int E) {
    int t = blockIdx.x * blockDim.x + threadIdx.x;
    if (t < E) atomicAdd(&cnt[ei[E + t]], 1);
}

// ---------------- K4b: 3-phase scan ----------------
__global__ void k_scan1(const int* __restrict__ cnt, int* __restrict__ off,
                        int* __restrict__ bsum, int N) {
    __shared__ int wpre[16];
    int i = blockIdx.x * 1024 + threadIdx.x;
    int lane = threadIdx.x & 63, wid = threadIdx.x >> 6;
    int v = (i < N) ? cnt[i] : 0;
    int s = v;
    #pragma unroll
    for (int d = 1; d < 64; d <<= 1) {
        int t = __shfl_up(s, d);
        if (lane >= d) s += t;
    }
    if (lane == 63) wpre[wid] = s;
    __syncthreads();
    if (threadIdx.x == 0) {
        int run = 0;
        #pragma unroll
        for (int q = 0; q < 16; ++q) { int t = wpre[q]; wpre[q] = run; run += t; }
        bsum[blockIdx.x] = run;
    }
    __syncthreads();
    if (i < N) off[i] = wpre[wid] + s - v;  // exclusive within block
}

__global__ void k_scan2(const int* __restrict__ bsum, int* __restrict__ bsx,
                        int* __restrict__ offN, int nb) {
    int lane = threadIdx.x;  // 64 threads, nb <= 64
    int v = (lane < nb) ? bsum[lane] : 0;
    int s = v;
    #pragma unroll
    for (int d = 1; d < 64; d <<= 1) {
        int t = __shfl_up(s, d);
        if (lane >= d) s += t;
    }
    if (lane < nb) bsx[lane] = s - v;
    if (lane == 63) *offN = s;
}

__global__ void k_scan3(int* __restrict__ off, const int* __restrict__ bsx, int N) {
    int i = blockIdx.x * 1024 + threadIdx.x;
    if (i < N) off[i] += bsx[blockIdx.x];
}

// ---------------- K4c: scatter src + fp16 attrs into CSR order ----------------
__global__ void k_scatter(const int* __restrict__ ei, const float* __restrict__ ea,
                          const int* __restrict__ off, int* __restrict__ cur,
                          int* __restrict__ esrc, h8* __restrict__ eac, int E) {
    int t = blockIdx.x * blockDim.x + threadIdx.x;
    if (t >= E) return;
    int dst = ei[E + t];
    int pos = off[dst] + atomicAdd(&cur[dst], 1);
    esrc[pos] = ei[t];
    float4 a0 = *(const float4*)(ea + (size_t)t * EDIM);
    float4 a1 = *(const float4*)(ea + (size_t)t * EDIM + 4);
    h8 v;
    v[0] = (_Float16)a0.x; v[1] = (_Float16)a0.y; v[2] = (_Float16)a0.z; v[3] = (_Float16)a0.w;
    v[4] = (_Float16)a1.x; v[5] = (_Float16)a1.y; v[6] = (_Float16)a1.z; v[7] = (_Float16)a1.w;
    eac[pos] = v;
}

// ---------------- K5: one wave per dst node, scalarized CSR gather ----------------
__global__ void k_gather(const int* __restrict__ esrc, const h8* __restrict__ eac,
                         const float* __restrict__ We, const float* __restrict__ att,
                         const _Float16* __restrict__ xh,
                         const float* __restrict__ loop_emb, const float* __restrict__ bias,
                         const int* __restrict__ off,
                         float* __restrict__ out, int N) {
    int wave = (blockIdx.x * blockDim.x + threadIdx.x) >> 6;
    int lane = threadIdx.x & 63;
    if (wave >= N) return;
    int dst = __builtin_amdgcn_readfirstlane(wave);
    int hc = lane * 2;

    h2 we2[EDIM];
    #pragma unroll
    for (int d = 0; d < EDIM; ++d) {
        we2[d][0] = (_Float16)We[d * HC + hc];
        we2[d][1] = (_Float16)We[d * HC + hc + 1];
    }
    h2 att2; att2[0] = (_Float16)att[hc]; att2[1] = (_Float16)att[hc + 1];
    h2 xr2 = *(const h2*)(xh + (size_t)dst * 256 + HC + hc);
    float xr0f = (float)xr2[0], xr1f = (float)xr2[1];

    float acc0 = 0.f, acc1 = 0.f, segw = 0.f;

    // self-loop (src = dst, emb = loop_emb), fp32 path
    {
        h2 xl2 = *(const h2*)(xh + (size_t)dst * 256 + hc);
        float x0 = (float)xl2[0], x1 = (float)xl2[1];
        float m0 = lrelu(x0 + xr0f + loop_emb[hc]);
        float m1 = lrelu(x1 + xr1f + loop_emb[hc + 1]);
        float p = m0 * (float)att2[0] + m1 * (float)att2[1];
        p += __shfl_xor(p, 1); p += __shfl_xor(p, 2); p += __shfl_xor(p, 4);
        float w = __expf(p);
        segw += w; acc0 += w * x0; acc1 += w * x1;
    }

    int beg = off[dst], end = off[dst + 1];
    int i = beg;
    int src_c = 0; h8 a_c = {};
    if (i < end) { src_c = esrc[i]; a_c = eac[i]; }
    const h2 zero2 = {};
    const h2 neg2 = {(_Float16)NEG, (_Float16)NEG};
    while (i < end) {
        int src = src_c; h8 a8 = a_c;
        int inext = i + 1;
        if (inext < end) { src_c = esrc[inext]; a_c = eac[inext]; }
        h2 xl2 = *(const h2*)(xh + (size_t)src * 256 + hc);
        h2 e2 = {};
        #pragma unroll
        for (int d = 0; d < EDIM; ++d) {
            h2 ad; ad[0] = a8[d]; ad[1] = a8[d];
            e2 += ad * we2[d];
        }
        h2 m2 = xl2 + xr2 + e2;
        h2 mp = __builtin_elementwise_max(m2, zero2);
        h2 mn = __builtin_elementwise_min(m2, zero2);
        m2 = mp + mn * neg2;
#if __has_builtin(__builtin_amdgcn_fdot2)
        float p = __builtin_amdgcn_fdot2(m2, att2, 0.f, false);
#else
        float p = (float)m2[0] * (float)att2[0] + (float)m2[1] * (float)att2[1];
#endif
        p += __shfl_xor(p, 1); p += __shfl_xor(p, 2); p += __shfl_xor(p, 4);
        float w = __expf(p);
        segw += w;
        acc0 += w * (float)xl2[0];
        acc1 += w * (float)xl2[1];
        i = inext;
    }

    float inv = 1.f / (segw + 1e-16f);
    float2 o = make_float2(acc0 * inv + bias[hc], acc1 * inv + bias[hc + 1]);
    *(float2*)(out + (size_t)dst * HC + hc) = o;
}

extern "C" void kernel_launch(void* const* d_in, const int* in_sizes, int n_in,
                              void* d_out, int out_size, void* d_ws, size_t ws_size,
                              hipStream_t stream) {
    int N = in_sizes[0] / INC;
    int E = in_sizes[1] / 2;
    const float* x    = (const float*)d_in[0];
    const int*   ei   = (const int*)d_in[1];
    const float* ea   = (const float*)d_in[2];
    const float* Wl   = (const float*)d_in[3];
    const float* bl   = (const float*)d_in[4];
    const float* Wr   = (const float*)d_in[5];
    const float* br   = (const float*)d_in[6];
    const float* We   = (const float*)d_in[7];
    const float* att  = (const float*)d_in[8];
    const float* bias = (const float*)d_in[9];
    float* out = (float*)d_out;

    // workspace layout (16B-aligned blocks)
    _Float16* xh      = (_Float16*)d_ws;                   // N*256 halfs
    h8*       eac     = (h8*)(xh + (size_t)N * 256);       // E * 16B
    float* attr_sum   = (float*)(eac + E);                 // 8
    int*   cnt        = (int*)(attr_sum + 8);              // N
    int*   cur        = cnt + N;                           // N
    float* loop_emb   = (float*)(cur + N);                 // 128
    _Float16* packed  = (_Float16*)(loop_emb + HC);        // 32768 halfs
    int*   off        = (int*)(packed + 32768);            // N+1
    int*   esrc       = off + (N + 1);                     // E
    int*   bsum       = esrc + E;                          // 64
    int*   bsx        = bsum + 64;                         // 64

    // one memset covers attr_sum + cnt + cur (contiguous)
    hipMemsetAsync(attr_sum, 0, (8 + 2 * (size_t)N) * sizeof(float), stream);

    k_attr_sum<<<512, 256, 0, stream>>>(ea, attr_sum, E);
    k_loop_emb<<<1, HC, 0, stream>>>(attr_sum, We, loop_emb, 1.0f / (float)E);

    k_packW<<<16, 256, 0, stream>>>(Wl, Wr, packed);
    k_gemm_mfma<<<(N + 63) / 64, 256, 0, stream>>>(x, packed, bl, br, xh, N);

    k_hist<<<(E + 255) / 256, 256, 0, stream>>>(ei, cnt, E);
    int nb = (N + 1023) / 1024;
    k_scan1<<<nb, 1024, 0, stream>>>(cnt, off, bsum, N);
    k_scan2<<<1, 64, 0, stream>>>(bsum, bsx, off + N, nb);
    k_scan3<<<nb, 1024, 0, stream>>>(off, bsx, N);
    k_scatter<<<(E + 255) / 256, 256, 0, stream>>>(ei, ea, off, cur, esrc, eac, E);

    k_gather<<<(N * 64 + 255) / 256, 256, 0, stream>>>(esrc, eac, We, att, xh,
                                                       loop_emb, bias, off, out, N);
}

// Round 7
// 198.789 us; speedup vs baseline: 32.0348x; 1.1287x over previous
//
#include <hip/hip_runtime.h>

#define NHEAD 8
#define CH    16
#define HC    128   // NHEAD*CH
#define INC   128   // in channels
#define EDIM  8
#define NEG   0.2f

typedef _Float16 h8 __attribute__((ext_vector_type(8)));
typedef _Float16 h4 __attribute__((ext_vector_type(4)));
typedef _Float16 h2 __attribute__((ext_vector_type(2)));
typedef float    f4 __attribute__((ext_vector_type(4)));

__device__ __forceinline__ float lrelu(float v) { return v > 0.f ? v : NEG * v; }

// ---------------- K2: loop_emb = mean_attr @ W_e ; also emit fp16 We/att ----------------
__global__ void k_loop_emb(const float* __restrict__ attr_sum, const float* __restrict__ We,
                           const float* __restrict__ att, float* __restrict__ loop_emb,
                           _Float16* __restrict__ We16, _Float16* __restrict__ att16,
                           float invE) {
    int j = threadIdx.x;  // 0..127
    float acc = 0.f;
    #pragma unroll
    for (int d = 0; d < EDIM; ++d) {
        float w = We[d * HC + j];
        acc += attr_sum[d] * invE * w;
        We16[d * HC + j] = (_Float16)w;
    }
    loop_emb[j] = acc;
    att16[j] = (_Float16)att[j];
}

// ---------------- K3a: pack W = [Wl|Wr] into B-fragment order, fp16 ----------------
__global__ void k_packW(const float* __restrict__ Wl, const float* __restrict__ Wr,
                        _Float16* __restrict__ packed) {
    int id = blockIdx.x * blockDim.x + threadIdx.x;  // 0..4095
    int l  = id & 63;
    int kb = (id >> 6) & 3;
    int t  = id >> 8;           // 0..15
    int col = t * 16 + (l & 15);
    const float* W = (col < HC) ? Wl : Wr;
    int c = col & 127;
    int kbase = kb * 32 + (l >> 4) * 8;
    _Float16* dst = packed + (size_t)id * 8;
    #pragma unroll
    for (int j = 0; j < 8; ++j) dst[j] = (_Float16)W[(size_t)(kbase + j) * HC + c];
}

// ---------------- K3b: MFMA fp16 dual GEMM, 128 nodes/block ----------------
__global__ __launch_bounds__(256) void k_gemm_mfma(
        const float* __restrict__ x, const _Float16* __restrict__ packed,
        const float* __restrict__ bl, const float* __restrict__ br,
        _Float16* __restrict__ xh, int N) {
    int nb0 = blockIdx.x * 128;
    int w  = threadIdx.x >> 6;
    int l  = threadIdx.x & 63;

    const h8* pk = (const h8*)packed;
    h8 bfrag[4][4];  // [ntile][kb]
    #pragma unroll
    for (int t4 = 0; t4 < 4; ++t4)
        #pragma unroll
        for (int kb = 0; kb < 4; ++kb)
            bfrag[t4][kb] = pk[(size_t)(((w * 4 + t4) * 4 + kb) * 64 + l)];

    float bv[4];
    int cl = l & 15;
    #pragma unroll
    for (int t4 = 0; t4 < 4; ++t4) {
        int col = w * 64 + t4 * 16 + cl;
        bv[t4] = (col < HC) ? bl[col] : br[col - HC];
    }

    int g = l >> 4;
    int r0 = g * 4;
    for (int mt = 0; mt < 8; ++mt) {
        int m0 = nb0 + mt * 16;
        if (m0 >= N) break;
        int row = m0 + cl; if (row >= N) row = N - 1;
        const float* xp = x + (size_t)row * INC + g * 8;
        h8 afrag[4];
        #pragma unroll
        for (int kb = 0; kb < 4; ++kb) {
            float4 u = *(const float4*)(xp + kb * 32);
            float4 v = *(const float4*)(xp + kb * 32 + 4);
            h8 a;
            a[0] = (_Float16)u.x; a[1] = (_Float16)u.y; a[2] = (_Float16)u.z; a[3] = (_Float16)u.w;
            a[4] = (_Float16)v.x; a[5] = (_Float16)v.y; a[6] = (_Float16)v.z; a[7] = (_Float16)v.w;
            afrag[kb] = a;
        }
        f4 acc[4];
        #pragma unroll
        for (int t4 = 0; t4 < 4; ++t4) { f4 z = {0.f, 0.f, 0.f, 0.f}; acc[t4] = z; }
        #pragma unroll
        for (int kb = 0; kb < 4; ++kb)
            #pragma unroll
            for (int t4 = 0; t4 < 4; ++t4)
                acc[t4] = __builtin_amdgcn_mfma_f32_16x16x32_f16(afrag[kb], bfrag[t4][kb], acc[t4], 0, 0, 0);
        #pragma unroll
        for (int t4 = 0; t4 < 4; ++t4) {
            int col = w * 64 + t4 * 16 + cl;
            #pragma unroll
            for (int j = 0; j < 4; ++j) {
                int node = m0 + r0 + j;
                if (node < N) xh[(size_t)node * 256 + col] = (_Float16)(acc[t4][j] + bv[t4]);
            }
        }
    }
}

// ---------------- K4a: histogram of dst ----------------
__global__ void k_hist(const int* __restrict__ ei, int* __restrict__ cnt, int E) {
    int t = blockIdx.x * blockDim.x + threadIdx.x;
    if (t < E) atomicAdd(&cnt[ei[E + t]], 1);
}

// ---------------- K4b: 3-phase scan ----------------
__global__ void k_scan1(const int* __restrict__ cnt, int* __restrict__ off,
                        int* __restrict__ bsum, int N) {
    __shared__ int wpre[16];
    int i = blockIdx.x * 1024 + threadIdx.x;
    int lane = threadIdx.x & 63, wid = threadIdx.x >> 6;
    int v = (i < N) ? cnt[i] : 0;
    int s = v;
    #pragma unroll
    for (int d = 1; d < 64; d <<= 1) {
        int t = __shfl_up(s, d);
        if (lane >= d) s += t;
    }
    if (lane == 63) wpre[wid] = s;
    __syncthreads();
    if (threadIdx.x == 0) {
        int run = 0;
        #pragma unroll
        for (int q = 0; q < 16; ++q) { int t = wpre[q]; wpre[q] = run; run += t; }
        bsum[blockIdx.x] = run;
    }
    __syncthreads();
    if (i < N) off[i] = wpre[wid] + s - v;  // exclusive within block
}

__global__ void k_scan2(const int* __restrict__ bsum, int* __restrict__ bsx,
                        int* __restrict__ offN, int nb) {
    int lane = threadIdx.x;  // 64 threads, nb <= 64
    int v = (lane < nb) ? bsum[lane] : 0;
    int s = v;
    #pragma unroll
    for (int d = 1; d < 64; d <<= 1) {
        int t = __shfl_up(s, d);
        if (lane >= d) s += t;
    }
    if (lane < nb) bsx[lane] = s - v;
    if (lane == 63) *offN = s;
}

__global__ void k_scan3(int* __restrict__ off, const int* __restrict__ bsx, int N) {
    int i = blockIdx.x * 1024 + threadIdx.x;
    if (i < N) off[i] += bsx[blockIdx.x];
}

// ---------------- K4c: scatter src + fp16 attrs into CSR order; fused attr_sum ----------------
__global__ void k_scatter(const int* __restrict__ ei, const float* __restrict__ ea,
                          const int* __restrict__ off, int* __restrict__ cur,
                          int* __restrict__ esrc, h8* __restrict__ eac,
                          float* __restrict__ attr_sum, int E) {
    __shared__ float red[4][8];
    int t = blockIdx.x * blockDim.x + threadIdx.x;
    float av[8] = {0.f, 0.f, 0.f, 0.f, 0.f, 0.f, 0.f, 0.f};
    if (t < E) {
        int dst = ei[E + t];
        int pos = off[dst] + atomicAdd(&cur[dst], 1);
        esrc[pos] = ei[t];
        float4 a0 = *(const float4*)(ea + (size_t)t * EDIM);
        float4 a1 = *(const float4*)(ea + (size_t)t * EDIM + 4);
        av[0] = a0.x; av[1] = a0.y; av[2] = a0.z; av[3] = a0.w;
        av[4] = a1.x; av[5] = a1.y; av[6] = a1.z; av[7] = a1.w;
        h8 v;
        #pragma unroll
        for (int k = 0; k < 8; ++k) v[k] = (_Float16)av[k];
        eac[pos] = v;
    }
    // wave butterfly reduce each of the 8 dims
    #pragma unroll
    for (int m = 1; m < 64; m <<= 1) {
        #pragma unroll
        for (int k = 0; k < 8; ++k) av[k] += __shfl_xor(av[k], m);
    }
    int lane = threadIdx.x & 63, wid = threadIdx.x >> 6;
    if (lane == 0) {
        #pragma unroll
        for (int k = 0; k < 8; ++k) red[wid][k] = av[k];
    }
    __syncthreads();
    if (threadIdx.x < 8) {
        float s = red[0][threadIdx.x] + red[1][threadIdx.x] + red[2][threadIdx.x] + red[3][threadIdx.x];
        atomicAdd(&attr_sum[threadIdx.x], s);
    }
}

// ---------------- K5: wave per dst; 4 ch/lane, 2 edges/iter ----------------
__global__ void k_gather(const int* __restrict__ esrc, const h8* __restrict__ eac,
                         const _Float16* __restrict__ We16, const _Float16* __restrict__ att16,
                         const float* __restrict__ att,
                         const _Float16* __restrict__ xh,
                         const float* __restrict__ loop_emb, const float* __restrict__ bias,
                         const int* __restrict__ off, float* __restrict__ out, int N) {
    int wave = (blockIdx.x * blockDim.x + threadIdx.x) >> 6;
    int lane = threadIdx.x & 63;
    if (wave >= N) return;
    int dst = __builtin_amdgcn_readfirstlane(wave);
    int half = lane >> 5;
    int l = lane & 31;
    int c0 = l * 4;             // channel base; head = l>>2; logit group = 4 lanes

    h4 we4[EDIM];
    #pragma unroll
    for (int d = 0; d < EDIM; ++d) we4[d] = *(const h4*)(We16 + d * HC + c0);
    h2 attlo = *(const h2*)(att16 + c0);
    h2 atthi = *(const h2*)(att16 + c0 + 2);
    h4 xr4 = *(const h4*)(xh + (size_t)dst * 256 + HC + c0);
    float xr0 = (float)xr4[0], xr1 = (float)xr4[1], xr2f = (float)xr4[2], xr3 = (float)xr4[3];

    float acc0 = 0.f, acc1 = 0.f, acc2 = 0.f, acc3 = 0.f, segw = 0.f;

    // self-loop (fp32 path), counted once via half==0
    {
        h4 xl4 = *(const h4*)(xh + (size_t)dst * 256 + c0);
        float x0 = (float)xl4[0], x1 = (float)xl4[1], x2 = (float)xl4[2], x3 = (float)xl4[3];
        float4 le = *(const float4*)(loop_emb + c0);
        float4 af = *(const float4*)(att + c0);
        float m0 = lrelu(x0 + xr0 + le.x);
        float m1 = lrelu(x1 + xr1 + le.y);
        float m2 = lrelu(x2 + xr2f + le.z);
        float m3 = lrelu(x3 + xr3 + le.w);
        float p = m0 * af.x + m1 * af.y + m2 * af.z + m3 * af.w;
        p += __shfl_xor(p, 1); p += __shfl_xor(p, 2);
        float w = half ? 0.f : __expf(p);
        segw += w; acc0 += w * x0; acc1 += w * x1; acc2 += w * x2; acc3 += w * x3;
    }

    int beg = off[dst], end = off[dst + 1];
    if (beg < end) {
        const h2 ng2 = {(_Float16)NEG, (_Float16)NEG};
        const h4 z4 = {};
        h4 ng4; ng4[0] = ng2[0]; ng4[1] = ng2[0]; ng4[2] = ng2[0]; ng4[3] = ng2[0];
        // prefetch: indices 2 pairs ahead, xl 1 pair ahead
        int j1 = beg + half;     if (j1 >= end) j1 = end - 1;
        int j2 = beg + 2 + half; if (j2 >= end) j2 = end - 1;
        int src1 = esrc[j1]; h8 a1 = eac[j1];
        int src2 = esrc[j2]; h8 a2 = eac[j2];
        h4 xl1 = *(const h4*)(xh + (size_t)src1 * 256 + c0);
        for (int i = beg; i < end; i += 2) {
            bool valid = (i + half) < end;
            h8 a8 = a1; h4 xl4 = xl1;
            // advance pipeline
            a1 = a2; src1 = src2;
            xl1 = *(const h4*)(xh + (size_t)src1 * 256 + c0);
            int in4 = i + 4;
            if (in4 < end) {
                int jn = in4 + half; if (jn >= end) jn = end - 1;
                src2 = esrc[jn]; a2 = eac[jn];
            }
            // edge embedding for this lane's 4 channels
            h4 e4 = {};
            #pragma unroll
            for (int d = 0; d < EDIM; ++d) {
                h4 ad; ad[0] = a8[d]; ad[1] = a8[d]; ad[2] = a8[d]; ad[3] = a8[d];
                e4 += ad * we4[d];
            }
            h4 m4 = xl4 + xr4 + e4;
            h4 mp = __builtin_elementwise_max(m4, z4);
            h4 mn = __builtin_elementwise_min(m4, z4);
            m4 = mp + mn * ng4;
            h2 mlo; mlo[0] = m4[0]; mlo[1] = m4[1];
            h2 mhi; mhi[0] = m4[2]; mhi[1] = m4[3];
#if __has_builtin(__builtin_amdgcn_fdot2)
            float p = __builtin_amdgcn_fdot2(mlo, attlo, 0.f, false);
            p = __builtin_amdgcn_fdot2(mhi, atthi, p, false);
#else
            float p = (float)m4[0] * (float)attlo[0] + (float)m4[1] * (float)attlo[1]
                    + (float)m4[2] * (float)atthi[0] + (float)m4[3] * (float)atthi[1];
#endif
            p += __shfl_xor(p, 1);
            p += __shfl_xor(p, 2);
            float w = valid ? __expf(p) : 0.f;
            segw += w;
            acc0 += w * (float)xl4[0];
            acc1 += w * (float)xl4[1];
            acc2 += w * (float)xl4[2];
            acc3 += w * (float)xl4[3];
        }
    }

    // combine the two halves
    segw += __shfl_xor(segw, 32);
    acc0 += __shfl_xor(acc0, 32);
    acc1 += __shfl_xor(acc1, 32);
    acc2 += __shfl_xor(acc2, 32);
    acc3 += __shfl_xor(acc3, 32);

    if (half == 0) {
        float inv = 1.f / (segw + 1e-16f);
        float4 bv = *(const float4*)(bias + c0);
        float4 o;
        o.x = acc0 * inv + bv.x;
        o.y = acc1 * inv + bv.y;
        o.z = acc2 * inv + bv.z;
        o.w = acc3 * inv + bv.w;
        *(float4*)(out + (size_t)dst * HC + c0) = o;
    }
}

extern "C" void kernel_launch(void* const* d_in, const int* in_sizes, int n_in,
                              void* d_out, int out_size, void* d_ws, size_t ws_size,
                              hipStream_t stream) {
    int N = in_sizes[0] / INC;
    int E = in_sizes[1] / 2;
    const float* x    = (const float*)d_in[0];
    const int*   ei   = (const int*)d_in[1];
    const float* ea   = (const float*)d_in[2];
    const float* Wl   = (const float*)d_in[3];
    const float* bl   = (const float*)d_in[4];
    const float* Wr   = (const float*)d_in[5];
    const float* br   = (const float*)d_in[6];
    const float* We   = (const float*)d_in[7];
    const float* att  = (const float*)d_in[8];
    const float* bias = (const float*)d_in[9];
    float* out = (float*)d_out;

    // workspace layout (16B-aligned blocks)
    _Float16* xh      = (_Float16*)d_ws;                   // N*256 halfs
    h8*       eac     = (h8*)(xh + (size_t)N * 256);       // E * 16B
    float* attr_sum   = (float*)(eac + E);                 // 8
    int*   cnt        = (int*)(attr_sum + 8);              // N
    int*   cur        = cnt + N;                           // N
    float* loop_emb   = (float*)(cur + N);                 // 128
    _Float16* packed  = (_Float16*)(loop_emb + HC);        // 32768 halfs
    _Float16* We16    = packed + 32768;                    // 1024 halfs
    _Float16* att16   = We16 + 1024;                       // 128 halfs
    int*   off        = (int*)(att16 + 128);               // N+1
    int*   esrc       = off + (N + 1);                     // E
    int*   bsum       = esrc + E;                          // 64
    int*   bsx        = bsum + 64;                         // 64

    // one memset covers attr_sum + cnt + cur (contiguous)
    hipMemsetAsync(attr_sum, 0, (8 + 2 * (size_t)N) * sizeof(float), stream);

    k_packW<<<16, 256, 0, stream>>>(Wl, Wr, packed);
    k_gemm_mfma<<<(N + 127) / 128, 256, 0, stream>>>(x, packed, bl, br, xh, N);

    k_hist<<<(E + 255) / 256, 256, 0, stream>>>(ei, cnt, E);
    int nb = (N + 1023) / 1024;
    k_scan1<<<nb, 1024, 0, stream>>>(cnt, off, bsum, N);
    k_scan2<<<1, 64, 0, stream>>>(bsum, bsx, off + N, nb);
    k_scan3<<<nb, 1024, 0, stream>>>(off, bsx, N);
    k_scatter<<<(E + 255) / 256, 256, 0, stream>>>(ei, ea, off, cur, esrc, eac, attr_sum, E);

    k_loop_emb<<<1, HC, 0, stream>>>(attr_sum, We, att, loop_emb, We16, att16, 1.0f / (float)E);

    k_gather<<<(N * 64 + 255) / 256, 256, 0, stream>>>(esrc, eac, We16, att16, att, xh,
                                                       loop_emb, bias, off, out, N);
}

// Round 8
// 187.863 us; speedup vs baseline: 33.8979x; 1.0582x over previous
//
#include <hip/hip_runtime.h>

#define NHEAD 8
#define CH    16
#define HC    128   // NHEAD*CH
#define INC   128   // in channels
#define EDIM  8
#define NEG   0.2f

typedef _Float16 h8 __attribute__((ext_vector_type(8)));
typedef _Float16 h4 __attribute__((ext_vector_type(4)));
typedef _Float16 h2 __attribute__((ext_vector_type(2)));
typedef float    f4 __attribute__((ext_vector_type(4)));

__device__ __forceinline__ float lrelu(float v) { return v > 0.f ? v : NEG * v; }

// ---------------- K2: loop_emb = mean_attr @ W_e ; also emit fp16 We/att ----------------
__global__ void k_loop_emb(const float* __restrict__ attr_sum, const float* __restrict__ We,
                           const float* __restrict__ att, float* __restrict__ loop_emb,
                           _Float16* __restrict__ We16, _Float16* __restrict__ att16,
                           float invE) {
    int j = threadIdx.x;  // 0..127
    float acc = 0.f;
    #pragma unroll
    for (int d = 0; d < EDIM; ++d) {
        float w = We[d * HC + j];
        acc += attr_sum[d] * invE * w;
        We16[d * HC + j] = (_Float16)w;
    }
    loop_emb[j] = acc;
    att16[j] = (_Float16)att[j];
}

// ---------------- K3a: pack W = [Wl|Wr] into B-fragment order, fp16 ----------------
__global__ void k_packW(const float* __restrict__ Wl, const float* __restrict__ Wr,
                        _Float16* __restrict__ packed) {
    int id = blockIdx.x * blockDim.x + threadIdx.x;  // 0..4095
    int l  = id & 63;
    int kb = (id >> 6) & 3;
    int t  = id >> 8;           // 0..15
    int col = t * 16 + (l & 15);
    const float* W = (col < HC) ? Wl : Wr;
    int c = col & 127;
    int kbase = kb * 32 + (l >> 4) * 8;
    _Float16* dst = packed + (size_t)id * 8;
    #pragma unroll
    for (int j = 0; j < 8; ++j) dst[j] = (_Float16)W[(size_t)(kbase + j) * HC + c];
}

// ---------------- K3b: MFMA fp16 dual GEMM, 128 nodes/block, LDS-coalesced stores ----------------
__global__ __launch_bounds__(256) void k_gemm_mfma(
        const float* __restrict__ x, const _Float16* __restrict__ packed,
        const float* __restrict__ bl, const float* __restrict__ br,
        _Float16* __restrict__ xh, int N) {
    __shared__ _Float16 st[16][264];   // +8 pad: avoids 4-way ds_write bank conflict
    int nb0 = blockIdx.x * 128;
    int w  = threadIdx.x >> 6;
    int l  = threadIdx.x & 63;

    const h8* pk = (const h8*)packed;
    h8 bfrag[4][4];  // [ntile][kb]
    #pragma unroll
    for (int t4 = 0; t4 < 4; ++t4)
        #pragma unroll
        for (int kb = 0; kb < 4; ++kb)
            bfrag[t4][kb] = pk[(size_t)(((w * 4 + t4) * 4 + kb) * 64 + l)];

    float bv[4];
    int cl = l & 15;
    #pragma unroll
    for (int t4 = 0; t4 < 4; ++t4) {
        int col = w * 64 + t4 * 16 + cl;
        bv[t4] = (col < HC) ? bl[col] : br[col - HC];
    }

    int g = l >> 4;
    int r0 = g * 4;
    for (int mt = 0; mt < 8; ++mt) {
        int m0 = nb0 + mt * 16;
        if (m0 >= N) break;
        int row = m0 + cl; if (row >= N) row = N - 1;
        const float* xp = x + (size_t)row * INC + g * 8;
        h8 afrag[4];
        #pragma unroll
        for (int kb = 0; kb < 4; ++kb) {
            float4 u = *(const float4*)(xp + kb * 32);
            float4 v = *(const float4*)(xp + kb * 32 + 4);
            h8 a;
            a[0] = (_Float16)u.x; a[1] = (_Float16)u.y; a[2] = (_Float16)u.z; a[3] = (_Float16)u.w;
            a[4] = (_Float16)v.x; a[5] = (_Float16)v.y; a[6] = (_Float16)v.z; a[7] = (_Float16)v.w;
            afrag[kb] = a;
        }
        f4 acc[4];
        #pragma unroll
        for (int t4 = 0; t4 < 4; ++t4) { f4 z = {0.f, 0.f, 0.f, 0.f}; acc[t4] = z; }
        #pragma unroll
        for (int kb = 0; kb < 4; ++kb)
            #pragma unroll
            for (int t4 = 0; t4 < 4; ++t4)
                acc[t4] = __builtin_amdgcn_mfma_f32_16x16x32_f16(afrag[kb], bfrag[t4][kb], acc[t4], 0, 0, 0);
        // stage to LDS (fragment layout), then store rows coalesced
        #pragma unroll
        for (int t4 = 0; t4 < 4; ++t4) {
            int col = w * 64 + t4 * 16 + cl;
            #pragma unroll
            for (int j = 0; j < 4; ++j)
                st[r0 + j][col] = (_Float16)(acc[t4][j] + bv[t4]);
        }
        __syncthreads();
        #pragma unroll
        for (int q = 0; q < 2; ++q) {
            int cch = threadIdx.x + 256 * q;      // 0..511 chunks of 8 halfs
            int r = cch >> 5, ch = (cch & 31) * 8;
            int node = m0 + r;
            if (node < N) *(h8*)(xh + (size_t)node * 256 + ch) = *(const h8*)&st[r][ch];
        }
        __syncthreads();
    }
}

// ---------------- K4a: histogram of dst + rank within dst ----------------
__global__ void k_hist(const int* __restrict__ ei, int* __restrict__ cnt,
                       int* __restrict__ rank, int E) {
    int t = blockIdx.x * blockDim.x + threadIdx.x;
    if (t < E) rank[t] = atomicAdd(&cnt[ei[E + t]], 1);
}

// ---------------- K4b: 2-phase scan (block-local + block-sum scan) ----------------
__global__ void k_scan1(const int* __restrict__ cnt, int* __restrict__ off,
                        int* __restrict__ bsum, int N) {
    __shared__ int wpre[16];
    int i = blockIdx.x * 1024 + threadIdx.x;
    int lane = threadIdx.x & 63, wid = threadIdx.x >> 6;
    int v = (i < N) ? cnt[i] : 0;
    int s = v;
    #pragma unroll
    for (int d = 1; d < 64; d <<= 1) {
        int t = __shfl_up(s, d);
        if (lane >= d) s += t;
    }
    if (lane == 63) wpre[wid] = s;
    __syncthreads();
    if (threadIdx.x == 0) {
        int run = 0;
        #pragma unroll
        for (int q = 0; q < 16; ++q) { int t = wpre[q]; wpre[q] = run; run += t; }
        bsum[blockIdx.x] = run;
    }
    __syncthreads();
    if (i <= N) off[i] = wpre[wid] + s - v;  // exclusive within block (i==N: tail sentinel)
}

__global__ void k_scan2(const int* __restrict__ bsum, int* __restrict__ bsx, int nb) {
    int lane = threadIdx.x;  // 64 threads, nb <= 64
    int v = (lane < nb) ? bsum[lane] : 0;
    int s = v;
    #pragma unroll
    for (int d = 1; d < 64; d <<= 1) {
        int t = __shfl_up(s, d);
        if (lane >= d) s += t;
    }
    if (lane < nb) bsx[lane] = s - v;  // exclusive block prefix
}

// ---------------- K4c: scatter (no atomics) + fused attr_sum reduction ----------------
__global__ void k_scatter(const int* __restrict__ ei, const float* __restrict__ ea,
                          const int* __restrict__ off, const int* __restrict__ bsx,
                          const int* __restrict__ rank,
                          int* __restrict__ esrc, h8* __restrict__ eac,
                          float* __restrict__ attr_sum, int E) {
    __shared__ float red[4][8];
    int t = blockIdx.x * blockDim.x + threadIdx.x;
    float av[8] = {0.f, 0.f, 0.f, 0.f, 0.f, 0.f, 0.f, 0.f};
    if (t < E) {
        int dst = ei[E + t];
        int pos = off[dst] + bsx[dst >> 10] + rank[t];
        esrc[pos] = ei[t];
        float4 a0 = *(const float4*)(ea + (size_t)t * EDIM);
        float4 a1 = *(const float4*)(ea + (size_t)t * EDIM + 4);
        av[0] = a0.x; av[1] = a0.y; av[2] = a0.z; av[3] = a0.w;
        av[4] = a1.x; av[5] = a1.y; av[6] = a1.z; av[7] = a1.w;
        h8 v;
        #pragma unroll
        for (int k = 0; k < 8; ++k) v[k] = (_Float16)av[k];
        eac[pos] = v;
    }
    #pragma unroll
    for (int m = 1; m < 64; m <<= 1) {
        #pragma unroll
        for (int k = 0; k < 8; ++k) av[k] += __shfl_xor(av[k], m);
    }
    int lane = threadIdx.x & 63, wid = threadIdx.x >> 6;
    if (lane == 0) {
        #pragma unroll
        for (int k = 0; k < 8; ++k) red[wid][k] = av[k];
    }
    __syncthreads();
    if (threadIdx.x < 8) {
        float s = red[0][threadIdx.x] + red[1][threadIdx.x] + red[2][threadIdx.x] + red[3][threadIdx.x];
        atomicAdd(&attr_sum[threadIdx.x], s);
    }
}

// ---------------- K5: wave per dst; 4 ch/lane, 2 edges/iter, depth-2 xl pipeline ----------------
__global__ void k_gather(const int* __restrict__ esrc, const h8* __restrict__ eac,
                         const _Float16* __restrict__ We16, const _Float16* __restrict__ att16,
                         const float* __restrict__ att,
                         const _Float16* __restrict__ xh,
                         const float* __restrict__ loop_emb, const float* __restrict__ bias,
                         const int* __restrict__ off, const int* __restrict__ bsx,
                         float* __restrict__ out, int N) {
    int wave = (blockIdx.x * blockDim.x + threadIdx.x) >> 6;
    int lane = threadIdx.x & 63;
    if (wave >= N) return;
    int dst = __builtin_amdgcn_readfirstlane(wave);
    int half = lane >> 5;
    int l = lane & 31;
    int c0 = l * 4;             // channel base; head = l>>2; logit group = 4 lanes

    h4 we4[EDIM];
    #pragma unroll
    for (int d = 0; d < EDIM; ++d) we4[d] = *(const h4*)(We16 + d * HC + c0);
    h2 attlo = *(const h2*)(att16 + c0);
    h2 atthi = *(const h2*)(att16 + c0 + 2);
    h4 xr4 = *(const h4*)(xh + (size_t)dst * 256 + HC + c0);
    float xr0 = (float)xr4[0], xr1 = (float)xr4[1], xr2f = (float)xr4[2], xr3 = (float)xr4[3];

    float acc0 = 0.f, acc1 = 0.f, acc2 = 0.f, acc3 = 0.f, segw = 0.f;

    // self-loop (fp32 path), counted once via half==0
    {
        h4 xl4 = *(const h4*)(xh + (size_t)dst * 256 + c0);
        float x0 = (float)xl4[0], x1 = (float)xl4[1], x2 = (float)xl4[2], x3 = (float)xl4[3];
        float4 le = *(const float4*)(loop_emb + c0);
        float4 af = *(const float4*)(att + c0);
        float m0 = lrelu(x0 + xr0 + le.x);
        float m1 = lrelu(x1 + xr1 + le.y);
        float m2 = lrelu(x2 + xr2f + le.z);
        float m3 = lrelu(x3 + xr3 + le.w);
        float p = m0 * af.x + m1 * af.y + m2 * af.z + m3 * af.w;
        p += __shfl_xor(p, 1); p += __shfl_xor(p, 2);
        float w = half ? 0.f : __expf(p);
        segw += w; acc0 += w * x0; acc1 += w * x1; acc2 += w * x2; acc3 += w * x3;
    }

    int beg = off[dst] + bsx[dst >> 10];
    int end = off[dst + 1] + bsx[(dst + 1) >> 10];
    if (beg < end) {
        const h4 z4 = {};
        h4 ng4; ng4[0] = (_Float16)NEG; ng4[1] = (_Float16)NEG; ng4[2] = (_Float16)NEG; ng4[3] = (_Float16)NEG;
        int last = end - 1;
        int j0 = beg + half;     if (j0 > last) j0 = last;
        int j1 = beg + 2 + half; if (j1 > last) j1 = last;
        int j2 = beg + 4 + half; if (j2 > last) j2 = last;
        int sA = esrc[j0]; h8 aA = eac[j0];
        int sB = esrc[j1]; h8 aB = eac[j1];
        int sC = esrc[j2]; h8 aC = eac[j2];
        h4 xlA = *(const h4*)(xh + (size_t)sA * 256 + c0);
        h4 xlB = *(const h4*)(xh + (size_t)sB * 256 + c0);
        for (int i = beg; i < end; i += 2) {
            // issue xl for iter+2 and indices for iter+3
            h4 xlC = *(const h4*)(xh + (size_t)sC * 256 + c0);
            int j3 = i + 6 + half; if (j3 > last) j3 = last;
            int sD = esrc[j3]; h8 aD = eac[j3];
            bool valid = (i + half) < end;
            // compute with aA / xlA (loaded 2 iterations ago)
            h4 e4 = {};
            #pragma unroll
            for (int d = 0; d < EDIM; ++d) {
                h4 ad; ad[0] = aA[d]; ad[1] = aA[d]; ad[2] = aA[d]; ad[3] = aA[d];
                e4 += ad * we4[d];
            }
            h4 m4 = xlA + xr4 + e4;
            h4 mp = __builtin_elementwise_max(m4, z4);
            h4 mn = __builtin_elementwise_min(m4, z4);
            m4 = mp + mn * ng4;
            h2 mlo; mlo[0] = m4[0]; mlo[1] = m4[1];
            h2 mhi; mhi[0] = m4[2]; mhi[1] = m4[3];
#if __has_builtin(__builtin_amdgcn_fdot2)
            float p = __builtin_amdgcn_fdot2(mlo, attlo, 0.f, false);
            p = __builtin_amdgcn_fdot2(mhi, atthi, p, false);
#else
            float p = (float)m4[0] * (float)attlo[0] + (float)m4[1] * (float)attlo[1]
                    + (float)m4[2] * (float)atthi[0] + (float)m4[3] * (float)atthi[1];
#endif
            p += __shfl_xor(p, 1);
            p += __shfl_xor(p, 2);
            float w = valid ? __expf(p) : 0.f;
            segw += w;
            acc0 += w * (float)xlA[0];
            acc1 += w * (float)xlA[1];
            acc2 += w * (float)xlA[2];
            acc3 += w * (float)xlA[3];
            // shift pipeline
            aA = aB; aB = aC; aC = aD;
            xlA = xlB; xlB = xlC;
            sC = sD;
        }
    }

    // combine the two halves
    segw += __shfl_xor(segw, 32);
    acc0 += __shfl_xor(acc0, 32);
    acc1 += __shfl_xor(acc1, 32);
    acc2 += __shfl_xor(acc2, 32);
    acc3 += __shfl_xor(acc3, 32);

    if (half == 0) {
        float inv = 1.f / (segw + 1e-16f);
        float4 bv = *(const float4*)(bias + c0);
        float4 o;
        o.x = acc0 * inv + bv.x;
        o.y = acc1 * inv + bv.y;
        o.z = acc2 * inv + bv.z;
        o.w = acc3 * inv + bv.w;
        *(float4*)(out + (size_t)dst * HC + c0) = o;
    }
}

extern "C" void kernel_launch(void* const* d_in, const int* in_sizes, int n_in,
                              void* d_out, int out_size, void* d_ws, size_t ws_size,
                              hipStream_t stream) {
    int N = in_sizes[0] / INC;
    int E = in_sizes[1] / 2;
    const float* x    = (const float*)d_in[0];
    const int*   ei   = (const int*)d_in[1];
    const float* ea   = (const float*)d_in[2];
    const float* Wl   = (const float*)d_in[3];
    const float* bl   = (const float*)d_in[4];
    const float* Wr   = (const float*)d_in[5];
    const float* br   = (const float*)d_in[6];
    const float* We   = (const float*)d_in[7];
    const float* att  = (const float*)d_in[8];
    const float* bias = (const float*)d_in[9];
    float* out = (float*)d_out;

    // workspace layout (16B-aligned blocks first)
    _Float16* xh      = (_Float16*)d_ws;                   // N*256 halfs
    h8*       eac     = (h8*)(xh + (size_t)N * 256);       // E * 16B
    float* attr_sum   = (float*)(eac + E);                 // 8
    int*   cnt        = (int*)(attr_sum + 8);              // N
    float* loop_emb   = (float*)(cnt + N);                 // 128
    _Float16* packed  = (_Float16*)(loop_emb + HC);        // 32768 halfs
    _Float16* We16    = packed + 32768;                    // 1024 halfs
    _Float16* att16   = We16 + 1024;                       // 128 halfs
    int*   off        = (int*)(att16 + 128);               // N+2
    int*   rank       = off + (N + 2);                     // E
    int*   esrc       = rank + E;                          // E
    int*   bsum       = esrc + E;                          // 64
    int*   bsx        = bsum + 64;                         // 64

    // one memset covers attr_sum + cnt (contiguous)
    hipMemsetAsync(attr_sum, 0, (8 + (size_t)N) * sizeof(float), stream);

    k_packW<<<16, 256, 0, stream>>>(Wl, Wr, packed);
    k_gemm_mfma<<<(N + 127) / 128, 256, 0, stream>>>(x, packed, bl, br, xh, N);

    k_hist<<<(E + 255) / 256, 256, 0, stream>>>(ei, cnt, rank, E);
    int nb = (N + 1 + 1023) / 1024;
    k_scan1<<<nb, 1024, 0, stream>>>(cnt, off, bsum, N);
    k_scan2<<<1, 64, 0, stream>>>(bsum, bsx, nb);
    k_scatter<<<(E + 255) / 256, 256, 0, stream>>>(ei, ea, off, bsx, rank, esrc, eac, attr_sum, E);

    k_loop_emb<<<1, HC, 0, stream>>>(attr_sum, We, att, loop_emb, We16, att16, 1.0f / (float)E);

    k_gather<<<(N * 64 + 255) / 256, 256, 0, stream>>>(esrc, eac, We16, att16, att, xh,
                                                       loop_emb, bias, off, bsx, out, N);
}

// Round 9
// 167.411 us; speedup vs baseline: 38.0393x; 1.1222x over previous
//
#include <hip/hip_runtime.h>

#define NHEAD 8
#define CH    16
#define HC    128   // NHEAD*CH
#define INC   128   // in channels
#define EDIM  8
#define NEG   0.2f

typedef _Float16 h8 __attribute__((ext_vector_type(8)));
typedef _Float16 h4 __attribute__((ext_vector_type(4)));
typedef _Float16 h2 __attribute__((ext_vector_type(2)));
typedef float    f4 __attribute__((ext_vector_type(4)));

__device__ __forceinline__ float lrelu(float v) { return v > 0.f ? v : NEG * v; }

__device__ __forceinline__ float dot2(h2 a, h2 b, float c) {
#if __has_builtin(__builtin_amdgcn_fdot2)
    return __builtin_amdgcn_fdot2(a, b, c, false);
#else
    return c + (float)a[0] * (float)b[0] + (float)a[1] * (float)b[1];
#endif
}

// ---------------- packW: W = [Wl|Wr] into B-fragment order, fp16 ----------------
__global__ void k_packW(const float* __restrict__ Wl, const float* __restrict__ Wr,
                        _Float16* __restrict__ packed) {
    int id = blockIdx.x * blockDim.x + threadIdx.x;  // 0..4095
    int l  = id & 63;
    int kb = (id >> 6) & 3;
    int t  = id >> 8;           // 0..15
    int col = t * 16 + (l & 15);
    const float* W = (col < HC) ? Wl : Wr;
    int c = col & 127;
    int kbase = kb * 32 + (l >> 4) * 8;
    _Float16* dst = packed + (size_t)id * 8;
    #pragma unroll
    for (int j = 0; j < 8; ++j) dst[j] = (_Float16)W[(size_t)(kbase + j) * HC + c];
}

// ---------------- phase1: fused {MFMA dual GEMM} + {hist/rank + attr_sum} ----------------
__global__ __launch_bounds__(256) void k_phase1(
        const float* __restrict__ x, const _Float16* __restrict__ packed,
        const float* __restrict__ bl, const float* __restrict__ br,
        _Float16* __restrict__ xh,
        const int* __restrict__ ei, const float* __restrict__ ea,
        int* __restrict__ cnt, int* __restrict__ rank, float* __restrict__ attr_sum,
        int N, int E, int gemmBlocks) {
    __shared__ _Float16 st[16][264];
    __shared__ float red[4][8];

    if ((int)blockIdx.x < gemmBlocks) {
        // ---- GEMM part: 128 nodes per block ----
        int nb0 = blockIdx.x * 128;
        int w  = threadIdx.x >> 6;
        int l  = threadIdx.x & 63;

        const h8* pk = (const h8*)packed;
        h8 bfrag[4][4];
        #pragma unroll
        for (int t4 = 0; t4 < 4; ++t4)
            #pragma unroll
            for (int kb = 0; kb < 4; ++kb)
                bfrag[t4][kb] = pk[(size_t)(((w * 4 + t4) * 4 + kb) * 64 + l)];

        float bv[4];
        int cl = l & 15;
        #pragma unroll
        for (int t4 = 0; t4 < 4; ++t4) {
            int col = w * 64 + t4 * 16 + cl;
            bv[t4] = (col < HC) ? bl[col] : br[col - HC];
        }

        int g = l >> 4;
        int r0 = g * 4;
        for (int mt = 0; mt < 8; ++mt) {
            int m0 = nb0 + mt * 16;
            if (m0 >= N) break;
            int row = m0 + cl; if (row >= N) row = N - 1;
            const float* xp = x + (size_t)row * INC + g * 8;
            h8 afrag[4];
            #pragma unroll
            for (int kb = 0; kb < 4; ++kb) {
                float4 u = *(const float4*)(xp + kb * 32);
                float4 v = *(const float4*)(xp + kb * 32 + 4);
                h8 a;
                a[0] = (_Float16)u.x; a[1] = (_Float16)u.y; a[2] = (_Float16)u.z; a[3] = (_Float16)u.w;
                a[4] = (_Float16)v.x; a[5] = (_Float16)v.y; a[6] = (_Float16)v.z; a[7] = (_Float16)v.w;
                afrag[kb] = a;
            }
            f4 acc[4];
            #pragma unroll
            for (int t4 = 0; t4 < 4; ++t4) { f4 z = {0.f, 0.f, 0.f, 0.f}; acc[t4] = z; }
            #pragma unroll
            for (int kb = 0; kb < 4; ++kb)
                #pragma unroll
                for (int t4 = 0; t4 < 4; ++t4)
                    acc[t4] = __builtin_amdgcn_mfma_f32_16x16x32_f16(afrag[kb], bfrag[t4][kb], acc[t4], 0, 0, 0);
            #pragma unroll
            for (int t4 = 0; t4 < 4; ++t4) {
                int col = w * 64 + t4 * 16 + cl;
                #pragma unroll
                for (int j = 0; j < 4; ++j)
                    st[r0 + j][col] = (_Float16)(acc[t4][j] + bv[t4]);
            }
            __syncthreads();
            #pragma unroll
            for (int q = 0; q < 2; ++q) {
                int cch = threadIdx.x + 256 * q;
                int r = cch >> 5, ch = (cch & 31) * 8;
                int node = m0 + r;
                if (node < N) *(h8*)(xh + (size_t)node * 256 + ch) = *(const h8*)&st[r][ch];
            }
            __syncthreads();
        }
    } else {
        // ---- hist part: rank + cnt + attr column sums ----
        int t = (blockIdx.x - gemmBlocks) * 256 + threadIdx.x;
        float av[8] = {0.f, 0.f, 0.f, 0.f, 0.f, 0.f, 0.f, 0.f};
        if (t < E) {
            rank[t] = atomicAdd(&cnt[ei[E + t]], 1);
            float4 a0 = *(const float4*)(ea + (size_t)t * EDIM);
            float4 a1 = *(const float4*)(ea + (size_t)t * EDIM + 4);
            av[0] = a0.x; av[1] = a0.y; av[2] = a0.z; av[3] = a0.w;
            av[4] = a1.x; av[5] = a1.y; av[6] = a1.z; av[7] = a1.w;
        }
        #pragma unroll
        for (int m = 1; m < 64; m <<= 1) {
            #pragma unroll
            for (int k = 0; k < 8; ++k) av[k] += __shfl_xor(av[k], m);
        }
        int lane = threadIdx.x & 63, wid = threadIdx.x >> 6;
        if (lane == 0) {
            #pragma unroll
            for (int k = 0; k < 8; ++k) red[wid][k] = av[k];
        }
        __syncthreads();
        if (threadIdx.x < 8) {
            float s = red[0][threadIdx.x] + red[1][threadIdx.x] + red[2][threadIdx.x] + red[3][threadIdx.x];
            atomicAdd(&attr_sum[threadIdx.x], s);
        }
    }
}

// ---------------- scan1: block-local exclusive scan ----------------
__global__ void k_scan1(const int* __restrict__ cnt, int* __restrict__ off,
                        int* __restrict__ bsum, int N) {
    __shared__ int wpre[16];
    int i = blockIdx.x * 1024 + threadIdx.x;
    int lane = threadIdx.x & 63, wid = threadIdx.x >> 6;
    int v = (i < N) ? cnt[i] : 0;
    int s = v;
    #pragma unroll
    for (int d = 1; d < 64; d <<= 1) {
        int t = __shfl_up(s, d);
        if (lane >= d) s += t;
    }
    if (lane == 63) wpre[wid] = s;
    __syncthreads();
    if (threadIdx.x == 0) {
        int run = 0;
        #pragma unroll
        for (int q = 0; q < 16; ++q) { int t = wpre[q]; wpre[q] = run; run += t; }
        bsum[blockIdx.x] = run;
    }
    __syncthreads();
    if (i <= N) off[i] = wpre[wid] + s - v;  // exclusive within block (i==N: tail sentinel)
}

// ---------------- scan2 + loop_emb/We16/att16 (fused, 1 block) ----------------
__global__ void k_scan2lo(const int* __restrict__ bsum, int* __restrict__ bsx, int nb,
                          const float* __restrict__ attr_sum, const float* __restrict__ We,
                          const float* __restrict__ att, float* __restrict__ loop_emb,
                          _Float16* __restrict__ We16, _Float16* __restrict__ att16,
                          float invE) {
    int tid = threadIdx.x;
    if (tid < 64) {                 // wave 0: scan of block sums
        int v = (tid < nb) ? bsum[tid] : 0;
        int s = v;
        #pragma unroll
        for (int d = 1; d < 64; d <<= 1) {
            int t = __shfl_up(s, d);
            if (tid >= d) s += t;
        }
        if (tid < nb) bsx[tid] = s - v;
    } else if (tid < 192) {         // waves 1-2: loop_emb + fp16 param copies
        int j = tid - 64;           // 0..127
        float acc = 0.f;
        #pragma unroll
        for (int d = 0; d < EDIM; ++d) {
            float w = We[d * HC + j];
            acc += attr_sum[d] * invE * w;
            We16[d * HC + j] = (_Float16)w;
        }
        loop_emb[j] = acc;
        att16[j] = (_Float16)att[j];
    }
}

// ---------------- scatter: CSR permute (no atomics) ----------------
__global__ void k_scatter(const int* __restrict__ ei, const float* __restrict__ ea,
                          const int* __restrict__ off, const int* __restrict__ bsx,
                          const int* __restrict__ rank,
                          int* __restrict__ esrc, h8* __restrict__ eac, int E) {
    int t = blockIdx.x * blockDim.x + threadIdx.x;
    if (t >= E) return;
    int dst = ei[E + t];
    int pos = off[dst] + bsx[dst >> 10] + rank[t];
    esrc[pos] = ei[t];
    float4 a0 = *(const float4*)(ea + (size_t)t * EDIM);
    float4 a1 = *(const float4*)(ea + (size_t)t * EDIM + 4);
    h8 v;
    v[0] = (_Float16)a0.x; v[1] = (_Float16)a0.y; v[2] = (_Float16)a0.z; v[3] = (_Float16)a0.w;
    v[4] = (_Float16)a1.x; v[5] = (_Float16)a1.y; v[6] = (_Float16)a1.z; v[7] = (_Float16)a1.w;
    eac[pos] = v;
}

// ---------------- gather: wave per dst; 8 ch/lane, 4 edges/stage, 2 stages/iter ----------------
__global__ __launch_bounds__(256) void k_gather(
        const int* __restrict__ esrc, const h8* __restrict__ eac,
        const _Float16* __restrict__ We16, const _Float16* __restrict__ att16,
        const float* __restrict__ attf, const _Float16* __restrict__ xh,
        const float* __restrict__ loop_emb, const float* __restrict__ bias,
        const int* __restrict__ off, const int* __restrict__ bsx,
        float* __restrict__ out, int N) {
    int wave = (blockIdx.x * blockDim.x + threadIdx.x) >> 6;
    int lane = threadIdx.x & 63;
    if (wave >= N) return;
    int dst = __builtin_amdgcn_readfirstlane(wave);
    int qid = lane >> 4;        // quarter = which edge of the group of 4
    int l   = lane & 15;
    int c0  = l * 8;            // 8 channels per lane; head = l>>1 (pair of lanes)

    h8 we8[EDIM];
    #pragma unroll
    for (int d = 0; d < EDIM; ++d) we8[d] = *(const h8*)(We16 + d * HC + c0);
    h2 att2[4];
    #pragma unroll
    for (int k = 0; k < 4; ++k) att2[k] = *(const h2*)(att16 + c0 + 2 * k);
    h8 xr8 = *(const h8*)(xh + (size_t)dst * 256 + HC + c0);

    const h8 z8 = {};
    h8 ng8;
    #pragma unroll
    for (int k = 0; k < 8; ++k) ng8[k] = (_Float16)NEG;

    float accv[8] = {0.f, 0.f, 0.f, 0.f, 0.f, 0.f, 0.f, 0.f};
    float segw = 0.f;

    auto PROC = [&](h8 a8, h8 x8, bool cond) {
        h8 e8 = {};
        #pragma unroll
        for (int d = 0; d < EDIM; ++d) {
            h8 ad = {a8[d], a8[d], a8[d], a8[d], a8[d], a8[d], a8[d], a8[d]};
            e8 += ad * we8[d];
        }
        h8 m8 = x8 + xr8 + e8;
        h8 mp = __builtin_elementwise_max(m8, z8);
        h8 mn = __builtin_elementwise_min(m8, z8);
        m8 = mp + mn * ng8;
        float p = 0.f;
        #pragma unroll
        for (int k = 0; k < 4; ++k) {
            h2 mm; mm[0] = m8[2 * k]; mm[1] = m8[2 * k + 1];
            p = dot2(mm, att2[k], p);
        }
        p += __shfl_xor(p, 1);          // head logit (pair of lanes within quarter)
        float w = cond ? __expf(p) : 0.f;
        segw += w;
        #pragma unroll
        for (int k = 0; k < 8; ++k) accv[k] += w * (float)x8[k];
    };

    // self-loop (fp32 path), counted once via qid==0
    {
        h8 xl8 = *(const h8*)(xh + (size_t)dst * 256 + c0);
        f4 le0 = *(const f4*)(loop_emb + c0), le1 = *(const f4*)(loop_emb + c0 + 4);
        f4 af0 = *(const f4*)(attf + c0),     af1 = *(const f4*)(attf + c0 + 4);
        float le[8] = {le0[0], le0[1], le0[2], le0[3], le1[0], le1[1], le1[2], le1[3]};
        float af[8] = {af0[0], af0[1], af0[2], af0[3], af1[0], af1[1], af1[2], af1[3]};
        float xf[8];
        float p = 0.f;
        #pragma unroll
        for (int k = 0; k < 8; ++k) {
            xf[k] = (float)xl8[k];
            p += lrelu(xf[k] + (float)xr8[k] + le[k]) * af[k];
        }
        p += __shfl_xor(p, 1);
        float w = (qid == 0) ? __expf(p) : 0.f;
        segw += w;
        #pragma unroll
        for (int k = 0; k < 8; ++k) accv[k] += w * xf[k];
    }

    int beg = off[dst] + bsx[dst >> 10];
    int end = off[dst + 1] + bsx[(dst + 1) >> 10];
    if (beg < end) {
        int last = end - 1;
        int j;
        j = beg + qid;          if (j > last) j = last;
        int sU = esrc[j]; h8 aU = eac[j];
        j = beg + 4 + qid;      if (j > last) j = last;
        int sV = esrc[j]; h8 aV = eac[j];
        h8 xU = *(const h8*)(xh + (size_t)sU * 256 + c0);
        h8 xV = *(const h8*)(xh + (size_t)sV * 256 + c0);
        j = beg + 8 + qid;      if (j > last) j = last;
        int sP = esrc[j];
        j = beg + 12 + qid;     if (j > last) j = last;
        int sQ = esrc[j];
        for (int i = beg; i < end; i += 8) {
            // stage i : slot U
            PROC(aU, xU, (i + qid) < end);
            {
                int jx = i + 8 + qid;  if (jx > last) jx = last;
                xU = *(const h8*)(xh + (size_t)sP * 256 + c0);   // x for stage i+8
                aU = eac[jx];
                int jf = i + 16 + qid; if (jf > last) jf = last;
                sP = esrc[jf];
            }
            // stage i+4 : slot V
            PROC(aV, xV, (i + 4 + qid) < end);
            {
                int jx = i + 12 + qid; if (jx > last) jx = last;
                xV = *(const h8*)(xh + (size_t)sQ * 256 + c0);   // x for stage i+12
                aV = eac[jx];
                int jf = i + 20 + qid; if (jf > last) jf = last;
                sQ = esrc[jf];
            }
        }
    }

    // combine quarters
    segw += __shfl_xor(segw, 16); segw += __shfl_xor(segw, 32);
    #pragma unroll
    for (int k = 0; k < 8; ++k) {
        accv[k] += __shfl_xor(accv[k], 16);
        accv[k] += __shfl_xor(accv[k], 32);
    }

    if (qid == 0) {
        float inv = 1.f / (segw + 1e-16f);
        f4 b0 = *(const f4*)(bias + c0), b1 = *(const f4*)(bias + c0 + 4);
        f4 o0, o1;
        o0[0] = accv[0] * inv + b0[0]; o0[1] = accv[1] * inv + b0[1];
        o0[2] = accv[2] * inv + b0[2]; o0[3] = accv[3] * inv + b0[3];
        o1[0] = accv[4] * inv + b1[0]; o1[1] = accv[5] * inv + b1[1];
        o1[2] = accv[6] * inv + b1[2]; o1[3] = accv[7] * inv + b1[3];
        *(f4*)(out + (size_t)dst * HC + c0)     = o0;
        *(f4*)(out + (size_t)dst * HC + c0 + 4) = o1;
    }
}

extern "C" void kernel_launch(void* const* d_in, const int* in_sizes, int n_in,
                              void* d_out, int out_size, void* d_ws, size_t ws_size,
                              hipStream_t stream) {
    int N = in_sizes[0] / INC;
    int E = in_sizes[1] / 2;
    const float* x    = (const float*)d_in[0];
    const int*   ei   = (const int*)d_in[1];
    const float* ea   = (const float*)d_in[2];
    const float* Wl   = (const float*)d_in[3];
    const float* bl   = (const float*)d_in[4];
    const float* Wr   = (const float*)d_in[5];
    const float* br   = (const float*)d_in[6];
    const float* We   = (const float*)d_in[7];
    const float* att  = (const float*)d_in[8];
    const float* bias = (const float*)d_in[9];
    float* out = (float*)d_out;

    // workspace layout (16B-aligned blocks first)
    _Float16* xh      = (_Float16*)d_ws;                   // N*256 halfs
    h8*       eac     = (h8*)(xh + (size_t)N * 256);       // E * 16B
    float* attr_sum   = (float*)(eac + E);                 // 8
    int*   cnt        = (int*)(attr_sum + 8);              // N
    float* loop_emb   = (float*)(cnt + N);                 // 128
    _Float16* packed  = (_Float16*)(loop_emb + HC);        // 32768 halfs
    _Float16* We16    = packed + 32768;                    // 1024 halfs
    _Float16* att16   = We16 + 1024;                       // 128 halfs
    int*   off        = (int*)(att16 + 128);               // N+2
    int*   rank       = off + (N + 2);                     // E
    int*   esrc       = rank + E;                          // E
    int*   bsum       = esrc + E;                          // 64
    int*   bsx        = bsum + 64;                         // 64

    // one memset covers attr_sum + cnt (contiguous)
    hipMemsetAsync(attr_sum, 0, (8 + (size_t)N) * sizeof(float), stream);

    k_packW<<<16, 256, 0, stream>>>(Wl, Wr, packed);

    int gemmBlocks = (N + 127) / 128;
    int histBlocks = (E + 255) / 256;
    k_phase1<<<gemmBlocks + histBlocks, 256, 0, stream>>>(x, packed, bl, br, xh,
                                                          ei, ea, cnt, rank, attr_sum,
                                                          N, E, gemmBlocks);

    int nb = (N + 1 + 1023) / 1024;
    k_scan1<<<nb, 1024, 0, stream>>>(cnt, off, bsum, N);
    k_scan2lo<<<1, 256, 0, stream>>>(bsum, bsx, nb, attr_sum, We, att,
                                     loop_emb, We16, att16, 1.0f / (float)E);
    k_scatter<<<histBlocks, 256, 0, stream>>>(ei, ea, off, bsx, rank, esrc, eac, E);

    k_gather<<<(N * 64 + 255) / 256, 256, 0, stream>>>(esrc, eac, We16, att16, att, xh,
                                                       loop_emb, bias, off, bsx, out, N);
}